// Round 3
// baseline (4921.415 us; speedup 1.0000x reference)
//
#include <hip/hip_runtime.h>
#include <hip/hip_bf16.h>

typedef __hip_bfloat16 bf16;
typedef __attribute__((ext_vector_type(8))) short short8;
typedef __attribute__((ext_vector_type(4))) float float4v;

#define BATCH 8
#define SEQ   1568            // 14*14*8 tokens per batch
#define M_TOK (BATCH*SEQ)     // 12544
#define DM    768
#define DI    1536
#define DS    16
#define DTR   48
#define NCLS  1000
#define LAYERS 4
#define CHUNK 112             // scan chunk length (7 tiles of 16)
#define NCH   14              // SEQ / CHUNK

__device__ __forceinline__ float b2f(bf16 v){ return __bfloat162float(v); }
__device__ __forceinline__ bf16  f2b(float v){ return __float2bfloat16(v); }
__device__ __forceinline__ float us2f(unsigned short u){
    unsigned v = ((unsigned)u) << 16; float f; __builtin_memcpy(&f, &v, 4); return f;
}

// ---------------------------------------------------------------- dtype probe
__global__ void detect_dtype(const unsigned short* __restrict__ probe, unsigned* __restrict__ flag)
{
    if (threadIdx.x == 0 && blockIdx.x == 0) flag[0] = (probe[0] == 0) ? 1u : 0u;  // 1 = fp32
}

__global__ __launch_bounds__(256)
void to_bf16(const unsigned* __restrict__ flag, const void* __restrict__ src,
             bf16* __restrict__ dst, int n)
{
    int i = blockIdx.x*256 + threadIdx.x;
    if (i >= n) return;
    dst[i] = flag[0] ? f2b(((const float*)src)[i]) : ((const bf16*)src)[i];
}

__global__ __launch_bounds__(256)
void to_f32(const unsigned* __restrict__ flag, const void* __restrict__ src,
            float* __restrict__ dst, int n)
{
    int i = blockIdx.x*256 + threadIdx.x;
    if (i >= n) return;
    dst[i] = flag[0] ? ((const float*)src)[i] : b2f(((const bf16*)src)[i]);
}

// ---------------------------------------------------------------- gather patches (per batch-group)
__global__ __launch_bounds__(256)
void gather_patches(const bf16* __restrict__ x, bf16* __restrict__ Ap, int b0)
{
    size_t idx = (size_t)blockIdx.x*256 + threadIdx.x;
    int i = (int)(idx & 255);
    int m = (int)(idx >> 8);
    int b = b0 + m / SEQ, s = m % SEQ;
    int hw = s >> 3, c = s & 7;
    int h = hw / 14, w = hw % 14;
    int p = i >> 4, q = i & 15;
    Ap[idx] = x[(((size_t)(b*8 + c)*224) + h*16 + p)*224 + w*16 + q];
}

// ---------------------------------------------------------------- MFMA GEMM (128x128 tile, BK=32)
// C[m,n] = sum_k A[m,k]*W[n,k]; A (M,K) bf16 lda, W (N,K) bf16 ldw.
// epi 0: Cb=bf16(acc); epi 1: Cb=bf16(softplus(acc+bias[n])); epi 2: Cf+=acc;
// epi 3: Cf=acc+bias[n]+chan[(m&7)*N+n]
__global__ __launch_bounds__(256)
void gemm_mfma(const bf16* __restrict__ A, int lda,
               const bf16* __restrict__ W, int ldw,
               float* __restrict__ Cf, bf16* __restrict__ Cb, int ldc,
               const float* __restrict__ bias, const float* __restrict__ chan,
               int M, int N, int K, int epi)
{
    __shared__ short As[128*40];   // 32 + 8 pad elems per row (80B stride, 16B aligned)
    __shared__ short Bs[128*40];
    int tid  = threadIdx.x;
    int m0   = blockIdx.x*128, n0 = blockIdx.y*128;
    int lane = tid & 63, wv = tid >> 6;
    int wm = (wv >> 1)*64, wn = (wv & 1)*64;
    int l15 = lane & 15, quad = lane >> 4;

    float4v acc[4][4];
    #pragma unroll
    for (int i = 0; i < 4; ++i)
        #pragma unroll
        for (int j = 0; j < 4; ++j) acc[i][j] = (float4v){0.f,0.f,0.f,0.f};

    const short8 zv8 = {0,0,0,0,0,0,0,0};
    for (int k0 = 0; k0 < K; k0 += 32) {
        #pragma unroll
        for (int u = 0; u < 2; ++u) {
            int c   = tid*2 + u;           // 512 chunks of 16B
            int row = c >> 2, ch = c & 3;
            bool kok = (k0 + ch*8 + 8) <= K;   // K is a multiple of 8
            short8 va = (kok && m0 + row < M)
                ? *(const short8*)((const short*)A + (size_t)(m0+row)*lda + k0 + ch*8) : zv8;
            *(short8*)(As + row*40 + ch*8) = va;
            short8 vb = (kok && n0 + row < N)
                ? *(const short8*)((const short*)W + (size_t)(n0+row)*ldw + k0 + ch*8) : zv8;
            *(short8*)(Bs + row*40 + ch*8) = vb;
        }
        __syncthreads();
        short8 av[4], bv[4];
        #pragma unroll
        for (int i = 0; i < 4; ++i) av[i] = *(const short8*)(As + (wm + i*16 + l15)*40 + quad*8);
        #pragma unroll
        for (int j = 0; j < 4; ++j) bv[j] = *(const short8*)(Bs + (wn + j*16 + l15)*40 + quad*8);
        #pragma unroll
        for (int i = 0; i < 4; ++i)
            #pragma unroll
            for (int j = 0; j < 4; ++j)
                acc[i][j] = __builtin_amdgcn_mfma_f32_16x16x32_bf16(av[i], bv[j], acc[i][j], 0, 0, 0);
        __syncthreads();
    }

    // C/D layout: col = lane&15, row = quad*4 + reg
    #pragma unroll
    for (int i = 0; i < 4; ++i) {
        #pragma unroll
        for (int j = 0; j < 4; ++j) {
            int gn = n0 + wn + j*16 + l15;
            if (gn >= N) continue;
            #pragma unroll
            for (int r = 0; r < 4; ++r) {
                int gm = m0 + wm + i*16 + quad*4 + r;
                if (gm >= M) continue;
                float v = acc[i][j][r];
                size_t off = (size_t)gm*ldc + gn;
                if (epi == 0)      Cb[off] = f2b(v);
                else if (epi == 1) {
                    v += bias[gn];
                    v = (v > 20.f) ? v : log1pf(__expf(v));
                    Cb[off] = f2b(v);
                }
                else if (epi == 2) Cf[off] += v;
                else               Cf[off] = v + bias[gn] + chan[(size_t)(gm & 7)*N + gn];
            }
        }
    }
}

// ---------------------------------------------------------------- LayerNorm 768 (fp32 in, bf16 out)
__global__ __launch_bounds__(256)
void ln768(const float* __restrict__ X, const float* __restrict__ w,
           const float* __restrict__ bb, bf16* __restrict__ out)
{
    __shared__ float red[8];
    size_t t = blockIdx.x;
    const float* x = X + t*DM;
    float v[3]; float s = 0.f, s2 = 0.f;
    #pragma unroll
    for (int r = 0; r < 3; ++r) {
        v[r] = x[threadIdx.x + 256*r];
        s += v[r]; s2 += v[r]*v[r];
    }
    #pragma unroll
    for (int o = 32; o; o >>= 1) { s += __shfl_down(s, o, 64); s2 += __shfl_down(s2, o, 64); }
    if ((threadIdx.x & 63) == 0) { red[threadIdx.x >> 6] = s; red[(threadIdx.x >> 6) + 4] = s2; }
    __syncthreads();
    s  = red[0]+red[1]+red[2]+red[3];
    s2 = red[4]+red[5]+red[6]+red[7];
    float mu  = s * (1.f/DM);
    float inv = rsqrtf(fmaxf(s2*(1.f/DM) - mu*mu, 0.f) + 1e-5f);
    #pragma unroll
    for (int r = 0; r < 3; ++r) {
        int i = threadIdx.x + 256*r;
        out[t*DM + i] = f2b((v[r]-mu)*inv*w[i] + bb[i]);
    }
}

// ---------------------------------------------------------------- causal depthwise conv (k=4) + silu
__global__ __launch_bounds__(256)
void conv_silu(const bf16* __restrict__ xh, const float* __restrict__ cw,
               const float* __restrict__ cb, bf16* __restrict__ xc)
{
    size_t idx = (size_t)blockIdx.x*256 + threadIdx.x;   // < g*SEQ*DI
    int d = (int)(idx % DI);
    int m = (int)(idx / DI);
    int b = m / SEQ, t = m % SEQ;                        // local batch
    float acc = cb[d];
    #pragma unroll
    for (int k = 0; k < 4; ++k) {
        int tt = t + k - 3;
        if (tt >= 0)
            acc += b2f(xh[(size_t)(b*SEQ + tt)*DI + d]) * cw[d*4 + k];
    }
    float sig = 1.f/(1.f + __expf(-acc));
    xc[idx] = f2b(acc*sig);
}

// ---------------------------------------------------------------- selective scan v6: chunked 2-pass,
// double-buffered async staging (T14). Per tile: global ushort4 loads for tile
// t+2 issued before compute of tile t; cvt+ds_write to alt buffer overlaps the
// other waves' compute. pass1: 1 barrier/tile; pass2: 2 (ys handoff).

__global__ __launch_bounds__(256)
void scan_pass1(const bf16* __restrict__ dt, const bf16* __restrict__ x,
                const bf16* __restrict__ dbc, const float* __restrict__ Alog,
                float* __restrict__ hend, float* __restrict__ Pprod, int nin)
{
    __shared__ float dtsT[2][16][20], xsT[2][16][20], BshT[2][16][20];
    int c  = blockIdx.x / nin;          // chunk 0..NCH-2
    int r  = blockIdx.x % nin;
    int b  = r / 96;
    int d0 = (r % 96) * 16;
    int tid = threadIdx.x;
    int s  = tid & 15;
    int dl = tid >> 4;
    int d  = d0 + dl;

    float A2 = -__expf(Alog[(size_t)d*DS + s]) * 1.44269504f;
    float h = 0.f, sdt = 0.f;

    int wv   = tid >> 6;
    int lane = tid & 63;
    int st = lane >> 2;      // staging timestep 0..15
    int sd = (lane & 3) * 4; // staging inner offset {0,4,8,12}
    int tbase = c * CHUNK;
    const int NT = CHUNK/16; // 7

    const unsigned short* sp0 = nullptr;
    size_t rstride = 0;
    float* dst0 = nullptr;
    {
        size_t rb = (size_t)(b*SEQ + st);
        if (wv == 0)      { sp0 = (const unsigned short*)dt  + rb*DI + d0 + sd; rstride = DI; dst0 = &dtsT[0][0][0]; }
        else if (wv == 1) { sp0 = (const unsigned short*)x   + rb*DI + d0 + sd; rstride = DI; dst0 = &xsT[0][0][0]; }
        else if (wv == 2) { sp0 = (const unsigned short*)dbc + rb*80 + DTR + sd; rstride = 80; dst0 = &BshT[0][0][0]; }
    }
    const size_t bufstride = 16*20;     // floats between buf0 and buf1

    ushort4 vr;
    if (wv < 3) {
        vr = *(const ushort4*)(sp0 + (size_t)tbase*rstride);        // tile 0
        dst0[(sd+0)*20 + st] = us2f(vr.x);
        dst0[(sd+1)*20 + st] = us2f(vr.y);
        dst0[(sd+2)*20 + st] = us2f(vr.z);
        dst0[(sd+3)*20 + st] = us2f(vr.w);
        vr = *(const ushort4*)(sp0 + (size_t)(tbase+16)*rstride);   // tile 1
    }
    __syncthreads();

    for (int t = 0; t < NT; ++t) {
        int cur = t & 1;
        if (wv < 3) {
            if (t+1 < NT) {
                float* dstp = dst0 + (size_t)(cur^1)*bufstride;
                dstp[(sd+0)*20 + st] = us2f(vr.x);
                dstp[(sd+1)*20 + st] = us2f(vr.y);
                dstp[(sd+2)*20 + st] = us2f(vr.z);
                dstp[(sd+3)*20 + st] = us2f(vr.w);
            }
            if (t+2 < NT)
                vr = *(const ushort4*)(sp0 + (size_t)(tbase+(t+2)*16)*rstride);
        }
        #pragma unroll
        for (int jj = 0; jj < 16; jj += 4) {
            float4v dtq = *(const float4v*)&dtsT[cur][dl][jj];
            float4v xq  = *(const float4v*)&xsT [cur][dl][jj];
            float4v Bq  = *(const float4v*)&BshT[cur][s][jj];
            #pragma unroll
            for (int k = 0; k < 4; ++k) {
                float dtv = dtq[k];
                h = exp2f(dtv*A2)*h + (dtv*xq[k])*Bq[k];
                sdt += dtv;
            }
        }
        __syncthreads();
    }
    size_t o = ((size_t)c*nin + r)*256 + tid;
    hend [o] = h;
    Pprod[o] = exp2f(A2*sdt);
}

__global__ __launch_bounds__(256)
void scan_mid(const float* __restrict__ hend, const float* __restrict__ Pprod,
              float* __restrict__ hstart, int nin)
{
    int r = blockIdx.x, tid = threadIdx.x;
    float h = 0.f;
    hstart[(size_t)r*256 + tid] = 0.f;
    for (int c = 1; c < NCH; ++c) {
        size_t p = ((size_t)(c-1)*nin + r)*256 + tid;
        h = Pprod[p]*h + hend[p];
        hstart[((size_t)c*nin + r)*256 + tid] = h;
    }
}

__global__ __launch_bounds__(256)
void scan_pass2(const bf16* __restrict__ dt, const bf16* __restrict__ x,
                const bf16* __restrict__ dbc, const float* __restrict__ Alog,
                const float* __restrict__ Dpar, const float* __restrict__ hstart,
                bf16* __restrict__ y, int nin)
{
    __shared__ float dtsT[2][16][20], xsT[2][16][20], BshT[2][16][20], CshT[2][16][20];
    __shared__ bf16  ys[16][16];
    int c  = blockIdx.x / nin;
    int r  = blockIdx.x % nin;
    int b  = r / 96;
    int d0 = (r % 96) * 16;
    int tid = threadIdx.x;
    int s  = tid & 15;
    int dl = tid >> 4;
    int d  = d0 + dl;

    float A2 = -__expf(Alog[(size_t)d*DS + s]) * 1.44269504f;
    float Dv = Dpar[d];
    float h  = hstart[((size_t)c*nin + r)*256 + tid];

    int wv   = tid >> 6;
    int lane = tid & 63;
    int st = lane >> 2;
    int sd = (lane & 3) * 4;
    int tbase = c * CHUNK;
    const int NT = CHUNK/16;

    const unsigned short* sp0;
    size_t rstride;
    float* dst0;
    {
        size_t rb = (size_t)(b*SEQ + st);
        if (wv == 0)      { sp0 = (const unsigned short*)dt  + rb*DI + d0 + sd;       rstride = DI; dst0 = &dtsT[0][0][0]; }
        else if (wv == 1) { sp0 = (const unsigned short*)x   + rb*DI + d0 + sd;       rstride = DI; dst0 = &xsT[0][0][0]; }
        else if (wv == 2) { sp0 = (const unsigned short*)dbc + rb*80 + DTR + sd;      rstride = 80; dst0 = &BshT[0][0][0]; }
        else              { sp0 = (const unsigned short*)dbc + rb*80 + DTR + DS + sd; rstride = 80; dst0 = &CshT[0][0][0]; }
    }
    const size_t bufstride = 16*20;

    ushort4 vr = *(const ushort4*)(sp0 + (size_t)tbase*rstride);     // tile 0
    dst0[(sd+0)*20 + st] = us2f(vr.x);
    dst0[(sd+1)*20 + st] = us2f(vr.y);
    dst0[(sd+2)*20 + st] = us2f(vr.z);
    dst0[(sd+3)*20 + st] = us2f(vr.w);
    vr = *(const ushort4*)(sp0 + (size_t)(tbase+16)*rstride);        // tile 1
    __syncthreads();

    for (int t = 0; t < NT; ++t) {
        int cur = t & 1;
        if (t+1 < NT) {
            float* dstp = dst0 + (size_t)(cur^1)*bufstride;
            dstp[(sd+0)*20 + st] = us2f(vr.x);
            dstp[(sd+1)*20 + st] = us2f(vr.y);
            dstp[(sd+2)*20 + st] = us2f(vr.z);
            dstp[(sd+3)*20 + st] = us2f(vr.w);
        }
        if (t+2 < NT)
            vr = *(const ushort4*)(sp0 + (size_t)(tbase+(t+2)*16)*rstride);

        #pragma unroll
        for (int jj = 0; jj < 16; jj += 4) {
            float4v dtq = *(const float4v*)&dtsT[cur][dl][jj];
            float4v xq  = *(const float4v*)&xsT [cur][dl][jj];
            float4v Bq  = *(const float4v*)&BshT[cur][s][jj];
            float4v Cq  = *(const float4v*)&CshT[cur][s][jj];
            #pragma unroll
            for (int k = 0; k < 4; ++k) {
                float dtv = dtq[k];
                float xv  = xq[k];
                h = exp2f(dtv*A2)*h + (dtv*xv)*Bq[k];
                float p = h*Cq[k];
                p += __shfl_xor(p, 1, 16);
                p += __shfl_xor(p, 2, 16);
                p += __shfl_xor(p, 4, 16);
                p += __shfl_xor(p, 8, 16);
                if (s == 0) ys[jj+k][dl] = f2b(p + Dv*xv);
            }
        }
        __syncthreads();                 // ys ready + next buf staged
        if (wv == 0) {
            size_t rowm = (size_t)(b*SEQ + tbase + t*16 + st);
            ushort4 vy = *(const ushort4*)((const unsigned short*)&ys[st][0] + sd);
            *(ushort4*)((unsigned short*)y + rowm*DI + d0 + sd) = vy;
        }
        __syncthreads();                 // ys consumed
    }
}

// ---------------------------------------------------------------- LN(1536) * silu(z) gate
__global__ __launch_bounds__(256)
void gate_ln(const bf16* __restrict__ y, const bf16* __restrict__ z,
             const float* __restrict__ w, const float* __restrict__ bb,
             bf16* __restrict__ out)
{
    __shared__ float red[8];
    size_t t = blockIdx.x;
    const bf16* yy = y + t*DI;
    const bf16* zz = z + t*DI;
    float v[6]; float s = 0.f, s2 = 0.f;
    #pragma unroll
    for (int r = 0; r < 6; ++r) {
        v[r] = b2f(yy[threadIdx.x + 256*r]);
        s += v[r]; s2 += v[r]*v[r];
    }
    #pragma unroll
    for (int o = 32; o; o >>= 1) { s += __shfl_down(s, o, 64); s2 += __shfl_down(s2, o, 64); }
    if ((threadIdx.x & 63) == 0) { red[threadIdx.x >> 6] = s; red[(threadIdx.x >> 6) + 4] = s2; }
    __syncthreads();
    s  = red[0]+red[1]+red[2]+red[3];
    s2 = red[4]+red[5]+red[6]+red[7];
    float mu  = s * (1.f/DI);
    float inv = rsqrtf(fmaxf(s2*(1.f/DI) - mu*mu, 0.f) + 1e-5f);
    #pragma unroll
    for (int r = 0; r < 6; ++r) {
        int i = threadIdx.x + 256*r;
        float zv = b2f(zz[i]);
        float sig = 1.f/(1.f + __expf(-zv));
        out[t*DI + i] = f2b(((v[r]-mu)*inv*w[i] + bb[i]) * (zv*sig));
    }
}

// ---------------------------------------------------------------- mean pool over tokens
__global__ __launch_bounds__(256)
void pool_kernel(const bf16* __restrict__ hf, float* __restrict__ pooled)
{
    int idx = blockIdx.x*256 + threadIdx.x;   // < BATCH*DM
    int b = idx / DM, dm = idx % DM;
    const bf16* p = hf + (size_t)b*SEQ*DM + dm;
    float s = 0.f;
    for (int t = 0; t < SEQ; ++t) s += b2f(p[(size_t)t*DM]);
    pooled[idx] = s * (1.f/SEQ);
}

// ---------------------------------------------------------------- classifier head
__global__ __launch_bounds__(256)
void head_kernel(const unsigned* __restrict__ flag,
                 const float* __restrict__ pooled, const bf16* __restrict__ hw,
                 const float* __restrict__ hb, void* __restrict__ out)
{
    int idx = blockIdx.x*256 + threadIdx.x;
    if (idx >= BATCH*NCLS) return;
    int b = idx & 7, n = idx >> 3;
    const float* p = pooled + b*DM;
    const unsigned short* w = (const unsigned short*)hw + (size_t)n*DM;
    float acc = hb[n];
    for (int k = 0; k < DM; k += 4) {
        ushort4 wv = *(const ushort4*)(w + k);
        acc += p[k]*us2f(wv.x) + p[k+1]*us2f(wv.y) + p[k+2]*us2f(wv.z) + p[k+3]*us2f(wv.w);
    }
    int o = b*NCLS + n;
    if (flag[0]) ((float*)out)[o] = acc;
    else         ((bf16*)out)[o]  = f2b(acc);
}

// ================================================================ launcher
extern "C" void kernel_launch(void* const* d_in, const int* in_sizes, int n_in,
                              void* d_out, int out_size, void* d_ws, size_t ws_size,
                              hipStream_t stream)
{
    (void)n_in; (void)out_size;
    dim3 blk(256);

    const bool is_f32[21] = { false, false, true, true, true, true, false, true, true,
                              false, false, true,  true, true, true, true, false,
                              true,  true,  false, true };

    size_t off = 0;
    auto carve = [&](size_t bytes) -> void* {
        void* q = (char*)d_ws + off;
        off += (bytes + 255) & ~(size_t)255;
        return q;
    };

    unsigned* flag = (unsigned*)carve(256);
    void* canon[21];
    for (int i = 0; i < 21; ++i)
        canon[i] = carve((size_t)in_sizes[i] * (is_f32[i] ? 4 : 2));

    float* residual = (float*)carve((size_t)M_TOK*DM*4);
    bf16*  hn       = (bf16*) carve((size_t)M_TOK*DM*2);
    float* pooled   = (float*)carve((size_t)BATCH*DM*4);

    const size_t scanbuf1 = (size_t)NCH*96*256*4;   // per g-unit, per array (1.31 MB)
    const size_t inner1 = 4*(((size_t)SEQ*DI*2 + 255) & ~(size_t)255)
                          + (((size_t)SEQ*80*2 + 255) & ~(size_t)255)
                          + 3*((scanbuf1 + 255) & ~(size_t)255);
    int g = 8;
    while (g > 1 && off + (size_t)g*inner1 > ws_size) g >>= 1;

    bf16* xh  = (bf16*)carve((size_t)g*SEQ*DI*2);   // also Ap / ybuf
    bf16* zh  = (bf16*)carve((size_t)g*SEQ*DI*2);
    bf16* xc  = (bf16*)carve((size_t)g*SEQ*DI*2);
    bf16* dtb = (bf16*)carve((size_t)g*SEQ*DI*2);   // also gated
    bf16* dbc = (bf16*)carve((size_t)g*SEQ*80*2);
    float* hend   = (float*)carve((size_t)g*scanbuf1);
    float* Pprod  = (float*)carve((size_t)g*scanbuf1);
    float* hstart = (float*)carve((size_t)g*scanbuf1);
    bf16* Ap    = xh;
    bf16* ybuf  = xh;
    bf16* gated = dtb;

    detect_dtype<<<1, 64, 0, stream>>>((const unsigned short*)d_in[4], flag);
    for (int i = 0; i < 21; ++i) {
        int n = in_sizes[i];
        int gr = (n + 255)/256;
        if (is_f32[i]) to_f32 <<<gr, blk, 0, stream>>>(flag, d_in[i], (float*)canon[i], n);
        else           to_bf16<<<gr, blk, 0, stream>>>(flag, d_in[i], (bf16*) canon[i], n);
    }

    const bf16*  xin   = (const bf16*) canon[0];
    const bf16*  pw    = (const bf16*) canon[1];
    const float* pb    = (const float*)canon[2];
    const float* chan  = (const float*)canon[3];
    const float* nw    = (const float*)canon[4];
    const float* nb    = (const float*)canon[5];
    const bf16*  ipw   = (const bf16*) canon[6];
    const float* cw    = (const float*)canon[7];
    const float* cb    = (const float*)canon[8];
    const bf16*  xpw   = (const bf16*) canon[9];
    const bf16*  dtw   = (const bf16*) canon[10];
    const float* dtbia = (const float*)canon[11];
    const float* Alog  = (const float*)canon[12];
    const float* Dpar  = (const float*)canon[13];
    const float* snw   = (const float*)canon[14];
    const float* snb   = (const float*)canon[15];
    const bf16*  opw   = (const bf16*) canon[16];
    const float* nfw   = (const float*)canon[17];
    const float* nfb   = (const float*)canon[18];
    const bf16*  hw    = (const bf16*) canon[19];
    const float* hb    = (const float*)canon[20];

    const int MG  = g*SEQ;
    const int GXm = (MG + 127)/128;       // MFMA grid (M)
    const int nin = g*96;                 // scan inner blocks per chunk

    // ---- patch embed -> residual (fp32), MFMA epi3 ----
    for (int b0 = 0; b0 < BATCH; b0 += g) {
        gather_patches<<<MG, blk, 0, stream>>>(xin, Ap, b0);
        dim3 gr(GXm, DM/128);
        gemm_mfma<<<gr, blk, 0, stream>>>(Ap, 256, pw, 256,
                                          residual + (size_t)b0*SEQ*DM, nullptr, DM,
                                          pb, chan, MG, DM, 256, 3);
    }

    for (int l = 0; l < LAYERS; ++l) {
        ln768<<<M_TOK, blk, 0, stream>>>(residual, nw + l*DM, nb + l*DM, hn);
        for (int b0 = 0; b0 < BATCH; b0 += g) {
            const bf16* hng = hn + (size_t)b0*SEQ*DM;
            {   dim3 gr(GXm, DI/128);   // in_proj halves (MFMA)
                gemm_mfma<<<gr, blk, 0, stream>>>(hng, DM, ipw + (size_t)l*2*DI*DM, DM,
                                                  nullptr, xh, DI, nullptr, nullptr,
                                                  MG, DI, DM, 0);
                gemm_mfma<<<gr, blk, 0, stream>>>(hng, DM, ipw + (size_t)l*2*DI*DM + (size_t)DI*DM, DM,
                                                  nullptr, zh, DI, nullptr, nullptr,
                                                  MG, DI, DM, 0);
            }
            conv_silu<<<(MG*DI)/256, blk, 0, stream>>>(xh, cw + (size_t)l*DI*4, cb + l*DI, xc);
            {   dim3 gr(GXm, 1);        // x_proj (MFMA, N=80 padded to one 128-tile)
                gemm_mfma<<<gr, blk, 0, stream>>>(xc, DI, xpw + (size_t)l*80*DI, DI,
                                                  nullptr, dbc, 80, nullptr, nullptr,
                                                  MG, 80, DI, 0);
            }
            {   dim3 gr(GXm, DI/128);   // dt_proj + softplus (MFMA, K=48 zero-padded)
                gemm_mfma<<<gr, blk, 0, stream>>>(dbc, 80, dtw + (size_t)l*DI*DTR, DTR,
                                                  nullptr, dtb, DI, dtbia + l*DI, nullptr,
                                                  MG, DI, DTR, 1);
            }
            scan_pass1<<<(NCH-1)*nin, blk, 0, stream>>>(dtb, xc, dbc,
                                                        Alog + (size_t)l*DI*DS,
                                                        hend, Pprod, nin);
            scan_mid<<<nin, blk, 0, stream>>>(hend, Pprod, hstart, nin);
            scan_pass2<<<NCH*nin, blk, 0, stream>>>(dtb, xc, dbc,
                                                    Alog + (size_t)l*DI*DS,
                                                    Dpar + l*DI, hstart, ybuf, nin);
            gate_ln<<<MG, blk, 0, stream>>>(ybuf, zh, snw + l*DI, snb + l*DI, gated);
            {   dim3 gr(GXm, DM/128);   // out_proj += residual (MFMA epi2)
                gemm_mfma<<<gr, blk, 0, stream>>>(gated, DI, opw + (size_t)l*DM*DI, DI,
                                                  residual + (size_t)b0*SEQ*DM, nullptr, DM,
                                                  nullptr, nullptr, MG, DM, DI, 2);
            }
        }
    }

    ln768<<<M_TOK, blk, 0, stream>>>(residual, nfw, nfb, hn);
    pool_kernel<<<(BATCH*DM)/256, blk, 0, stream>>>(hn, pooled);
    head_kernel<<<(BATCH*NCLS + 255)/256, blk, 0, stream>>>(flag, pooled, hw, hb, d_out);
}

// Round 4
// 4585.467 us; speedup vs baseline: 1.0733x; 1.0733x over previous
//
#include <hip/hip_runtime.h>
#include <hip/hip_bf16.h>

typedef __hip_bfloat16 bf16;
typedef __attribute__((ext_vector_type(8))) short short8;
typedef __attribute__((ext_vector_type(4))) float float4v;

#define BATCH 8
#define SEQ   1568            // 14*14*8 tokens per batch
#define M_TOK (BATCH*SEQ)     // 12544
#define DM    768
#define DI    1536
#define DS    16
#define DTR   48
#define NCLS  1000
#define LAYERS 4
#define CHUNK 112             // scan chunk length (7 tiles of 16)
#define NCH   14              // SEQ / CHUNK

__device__ __forceinline__ float b2f(bf16 v){ return __bfloat162float(v); }
__device__ __forceinline__ bf16  f2b(float v){ return __float2bfloat16(v); }
__device__ __forceinline__ float us2f(unsigned short u){
    unsigned v = ((unsigned)u) << 16; float f; __builtin_memcpy(&f, &v, 4); return f;
}
// async global->LDS, 16B per lane; LDS dest = uniform base + lane*16
__device__ __forceinline__ void gload_lds16(const void* g, void* l){
    __builtin_amdgcn_global_load_lds(
        (const __attribute__((address_space(1))) void*)g,
        (__attribute__((address_space(3))) void*)l, 16, 0, 0);
}

// ---------------------------------------------------------------- dtype probe
__global__ void detect_dtype(const unsigned short* __restrict__ probe, unsigned* __restrict__ flag)
{
    if (threadIdx.x == 0 && blockIdx.x == 0) flag[0] = (probe[0] == 0) ? 1u : 0u;  // 1 = fp32
}

__global__ __launch_bounds__(256)
void to_bf16(const unsigned* __restrict__ flag, const void* __restrict__ src,
             bf16* __restrict__ dst, int n)
{
    int i = blockIdx.x*256 + threadIdx.x;
    if (i >= n) return;
    dst[i] = flag[0] ? f2b(((const float*)src)[i]) : ((const bf16*)src)[i];
}

__global__ __launch_bounds__(256)
void to_f32(const unsigned* __restrict__ flag, const void* __restrict__ src,
            float* __restrict__ dst, int n)
{
    int i = blockIdx.x*256 + threadIdx.x;
    if (i >= n) return;
    dst[i] = flag[0] ? ((const float*)src)[i] : b2f(((const bf16*)src)[i]);
}

// ---------------------------------------------------------------- gather patches (per batch-group)
__global__ __launch_bounds__(256)
void gather_patches(const bf16* __restrict__ x, bf16* __restrict__ Ap, int b0)
{
    size_t idx = (size_t)blockIdx.x*256 + threadIdx.x;
    int i = (int)(idx & 255);
    int m = (int)(idx >> 8);
    int b = b0 + m / SEQ, s = m % SEQ;
    int hw = s >> 3, c = s & 7;
    int h = hw / 14, w = hw % 14;
    int p = i >> 4, q = i & 15;
    Ap[idx] = x[(((size_t)(b*8 + c)*224) + h*16 + p)*224 + w*16 + q];
}

// ---------------------------------------------------------------- MFMA GEMM, ragged-safe (128x128, BK=32)
// C[m,n] = sum_k A[m,k]*W[n,k]; guards on M/N rows + K 8-chunks.
// epi 0: Cb=bf16(acc); epi 1: Cb=bf16(softplus(acc+bias[n])); epi 2: Cf+=acc;
// epi 3: Cf=acc+bias[n]+chan[(m&7)*N+n]
__global__ __launch_bounds__(256)
void gemm_mfma(const bf16* __restrict__ A, int lda,
               const bf16* __restrict__ W, int ldw,
               float* __restrict__ Cf, bf16* __restrict__ Cb, int ldc,
               const float* __restrict__ bias, const float* __restrict__ chan,
               int M, int N, int K, int epi)
{
    __shared__ short As[128*40];   // 32 + 8 pad elems per row (80B stride, 16B aligned)
    __shared__ short Bs[128*40];
    int tid  = threadIdx.x;
    int m0   = blockIdx.x*128, n0 = blockIdx.y*128;
    int lane = tid & 63, wv = tid >> 6;
    int wm = (wv >> 1)*64, wn = (wv & 1)*64;
    int l15 = lane & 15, quad = lane >> 4;

    float4v acc[4][4];
    #pragma unroll
    for (int i = 0; i < 4; ++i)
        #pragma unroll
        for (int j = 0; j < 4; ++j) acc[i][j] = (float4v){0.f,0.f,0.f,0.f};

    const short8 zv8 = {0,0,0,0,0,0,0,0};
    for (int k0 = 0; k0 < K; k0 += 32) {
        #pragma unroll
        for (int u = 0; u < 2; ++u) {
            int c   = tid*2 + u;           // 512 chunks of 16B
            int row = c >> 2, ch = c & 3;
            bool kok = (k0 + ch*8 + 8) <= K;   // K is a multiple of 8
            short8 va = (kok && m0 + row < M)
                ? *(const short8*)((const short*)A + (size_t)(m0+row)*lda + k0 + ch*8) : zv8;
            *(short8*)(As + row*40 + ch*8) = va;
            short8 vb = (kok && n0 + row < N)
                ? *(const short8*)((const short*)W + (size_t)(n0+row)*ldw + k0 + ch*8) : zv8;
            *(short8*)(Bs + row*40 + ch*8) = vb;
        }
        __syncthreads();
        short8 av[4], bv[4];
        #pragma unroll
        for (int i = 0; i < 4; ++i) av[i] = *(const short8*)(As + (wm + i*16 + l15)*40 + quad*8);
        #pragma unroll
        for (int j = 0; j < 4; ++j) bv[j] = *(const short8*)(Bs + (wn + j*16 + l15)*40 + quad*8);
        #pragma unroll
        for (int i = 0; i < 4; ++i)
            #pragma unroll
            for (int j = 0; j < 4; ++j)
                acc[i][j] = __builtin_amdgcn_mfma_f32_16x16x32_bf16(av[i], bv[j], acc[i][j], 0, 0, 0);
        __syncthreads();
    }

    // C/D layout: col = lane&15, row = quad*4 + reg
    #pragma unroll
    for (int i = 0; i < 4; ++i) {
        #pragma unroll
        for (int j = 0; j < 4; ++j) {
            int gn = n0 + wn + j*16 + l15;
            if (gn >= N) continue;
            #pragma unroll
            for (int r = 0; r < 4; ++r) {
                int gm = m0 + wm + i*16 + quad*4 + r;
                if (gm >= M) continue;
                float v = acc[i][j][r];
                size_t off = (size_t)gm*ldc + gn;
                if (epi == 0)      Cb[off] = f2b(v);
                else if (epi == 1) {
                    v += bias[gn];
                    v = (v > 20.f) ? v : log1pf(__expf(v));
                    Cb[off] = f2b(v);
                }
                else if (epi == 2) Cf[off] += v;
                else               Cf[off] = v + bias[gn] + chan[(size_t)(gm & 7)*N + gn];
            }
        }
    }
}

// ---------------------------------------------------------------- MFMA GEMM fast path (m97 recipe)
// Requires M%128==0, N%128==0, K%32==0. Linear [128][32] LDS (64B rows),
// staged via global_load_lds dwordx4: wave wv loads chunks {2wv,2wv+1} of A and B;
// chunk c = 16 rows = 1024B, lane l -> row c*16+l/4, kofs (l&3)*8 -> LDS base+l*16.
__global__ __launch_bounds__(256)
void gemm_mfma_fast(const bf16* __restrict__ A, int lda,
                    const bf16* __restrict__ W, int ldw,
                    float* __restrict__ Cf, bf16* __restrict__ Cb, int ldc,
                    const float* __restrict__ bias, const float* __restrict__ chan,
                    int N, int K, int epi)
{
    __shared__ short As[128*32];
    __shared__ short Bs[128*32];
    int tid  = threadIdx.x;
    int m0   = blockIdx.x*128, n0 = blockIdx.y*128;
    int lane = tid & 63, wv = tid >> 6;
    int wm = (wv >> 1)*64, wn = (wv & 1)*64;
    int l15 = lane & 15, quad = lane >> 4;

    int srow = (lane >> 2);          // row within 16-row chunk
    int skof = (lane & 3) * 8;       // k element offset within row

    float4v acc[4][4];
    #pragma unroll
    for (int i = 0; i < 4; ++i)
        #pragma unroll
        for (int j = 0; j < 4; ++j) acc[i][j] = (float4v){0.f,0.f,0.f,0.f};

    const short* Ab = (const short*)A;
    const short* Wb = (const short*)W;

    for (int k0 = 0; k0 < K; k0 += 32) {
        #pragma unroll
        for (int u = 0; u < 2; ++u) {
            int c = wv*2 + u;                 // chunk 0..7
            int row = c*16 + srow;
            gload_lds16(Ab + (size_t)(m0+row)*lda + k0 + skof, As + c*512);
            gload_lds16(Wb + (size_t)(n0+row)*ldw + k0 + skof, Bs + c*512);
        }
        __syncthreads();                       // drains vmcnt (compiler-inserted)
        short8 av[4], bv[4];
        #pragma unroll
        for (int i = 0; i < 4; ++i) av[i] = *(const short8*)(As + (wm + i*16 + l15)*32 + quad*8);
        #pragma unroll
        for (int j = 0; j < 4; ++j) bv[j] = *(const short8*)(Bs + (wn + j*16 + l15)*32 + quad*8);
        #pragma unroll
        for (int i = 0; i < 4; ++i)
            #pragma unroll
            for (int j = 0; j < 4; ++j)
                acc[i][j] = __builtin_amdgcn_mfma_f32_16x16x32_bf16(av[i], bv[j], acc[i][j], 0, 0, 0);
        __syncthreads();
    }

    #pragma unroll
    for (int i = 0; i < 4; ++i) {
        #pragma unroll
        for (int j = 0; j < 4; ++j) {
            int gn = n0 + wn + j*16 + l15;
            #pragma unroll
            for (int r = 0; r < 4; ++r) {
                int gm = m0 + wm + i*16 + quad*4 + r;
                float v = acc[i][j][r];
                size_t off = (size_t)gm*ldc + gn;
                if (epi == 0)      Cb[off] = f2b(v);
                else if (epi == 1) {
                    v += bias[gn];
                    v = (v > 20.f) ? v : log1pf(__expf(v));
                    Cb[off] = f2b(v);
                }
                else if (epi == 2) Cf[off] += v;
                else               Cf[off] = v + bias[gn] + chan[(size_t)(gm & 7)*N + gn];
            }
        }
    }
}

// ---------------------------------------------------------------- LayerNorm 768 (fp32 in, bf16 out)
__global__ __launch_bounds__(256)
void ln768(const float* __restrict__ X, const float* __restrict__ w,
           const float* __restrict__ bb, bf16* __restrict__ out)
{
    __shared__ float red[8];
    size_t t = blockIdx.x;
    const float* x = X + t*DM;
    float v[3]; float s = 0.f, s2 = 0.f;
    #pragma unroll
    for (int r = 0; r < 3; ++r) {
        v[r] = x[threadIdx.x + 256*r];
        s += v[r]; s2 += v[r]*v[r];
    }
    #pragma unroll
    for (int o = 32; o; o >>= 1) { s += __shfl_down(s, o, 64); s2 += __shfl_down(s2, o, 64); }
    if ((threadIdx.x & 63) == 0) { red[threadIdx.x >> 6] = s; red[(threadIdx.x >> 6) + 4] = s2; }
    __syncthreads();
    s  = red[0]+red[1]+red[2]+red[3];
    s2 = red[4]+red[5]+red[6]+red[7];
    float mu  = s * (1.f/DM);
    float inv = rsqrtf(fmaxf(s2*(1.f/DM) - mu*mu, 0.f) + 1e-5f);
    #pragma unroll
    for (int r = 0; r < 3; ++r) {
        int i = threadIdx.x + 256*r;
        out[t*DM + i] = f2b((v[r]-mu)*inv*w[i] + bb[i]);
    }
}

// ---------------------------------------------------------------- causal depthwise conv (k=4) + silu
__global__ __launch_bounds__(256)
void conv_silu(const bf16* __restrict__ xh, const float* __restrict__ cw,
               const float* __restrict__ cb, bf16* __restrict__ xc)
{
    size_t idx = (size_t)blockIdx.x*256 + threadIdx.x;   // < g*SEQ*DI
    int d = (int)(idx % DI);
    int m = (int)(idx / DI);
    int b = m / SEQ, t = m % SEQ;                        // local batch
    float acc = cb[d];
    #pragma unroll
    for (int k = 0; k < 4; ++k) {
        int tt = t + k - 3;
        if (tt >= 0)
            acc += b2f(xh[(size_t)(b*SEQ + tt)*DI + d]) * cw[d*4 + k];
    }
    float sig = 1.f/(1.f + __expf(-acc));
    xc[idx] = f2b(acc*sig);
}

// ---------------------------------------------------------------- selective scan v6: chunked 2-pass,
// double-buffered async staging. pass1: local (hend,P) per chunk; mid: chunk-level
// scan; pass2: true recurrence seeded with hstart, emits y.

__global__ __launch_bounds__(256)
void scan_pass1(const bf16* __restrict__ dt, const bf16* __restrict__ x,
                const bf16* __restrict__ dbc, const float* __restrict__ Alog,
                float* __restrict__ hend, float* __restrict__ Pprod, int nin)
{
    __shared__ float dtsT[2][16][20], xsT[2][16][20], BshT[2][16][20];
    int c  = blockIdx.x / nin;          // chunk 0..NCH-2
    int r  = blockIdx.x % nin;
    int b  = r / 96;
    int d0 = (r % 96) * 16;
    int tid = threadIdx.x;
    int s  = tid & 15;
    int dl = tid >> 4;
    int d  = d0 + dl;

    float A2 = -__expf(Alog[(size_t)d*DS + s]) * 1.44269504f;
    float h = 0.f, sdt = 0.f;

    int wv   = tid >> 6;
    int lane = tid & 63;
    int st = lane >> 2;      // staging timestep 0..15
    int sd = (lane & 3) * 4; // staging inner offset {0,4,8,12}
    int tbase = c * CHUNK;
    const int NT = CHUNK/16; // 7

    const unsigned short* sp0 = nullptr;
    size_t rstride = 0;
    float* dst0 = nullptr;
    {
        size_t rb = (size_t)(b*SEQ + st);
        if (wv == 0)      { sp0 = (const unsigned short*)dt  + rb*DI + d0 + sd; rstride = DI; dst0 = &dtsT[0][0][0]; }
        else if (wv == 1) { sp0 = (const unsigned short*)x   + rb*DI + d0 + sd; rstride = DI; dst0 = &xsT[0][0][0]; }
        else if (wv == 2) { sp0 = (const unsigned short*)dbc + rb*80 + DTR + sd; rstride = 80; dst0 = &BshT[0][0][0]; }
    }
    const size_t bufstride = 16*20;     // floats between buf0 and buf1

    ushort4 vr;
    if (wv < 3) {
        vr = *(const ushort4*)(sp0 + (size_t)tbase*rstride);        // tile 0
        dst0[(sd+0)*20 + st] = us2f(vr.x);
        dst0[(sd+1)*20 + st] = us2f(vr.y);
        dst0[(sd+2)*20 + st] = us2f(vr.z);
        dst0[(sd+3)*20 + st] = us2f(vr.w);
        vr = *(const ushort4*)(sp0 + (size_t)(tbase+16)*rstride);   // tile 1
    }
    __syncthreads();

    for (int t = 0; t < NT; ++t) {
        int cur = t & 1;
        if (wv < 3) {
            if (t+1 < NT) {
                float* dstp = dst0 + (size_t)(cur^1)*bufstride;
                dstp[(sd+0)*20 + st] = us2f(vr.x);
                dstp[(sd+1)*20 + st] = us2f(vr.y);
                dstp[(sd+2)*20 + st] = us2f(vr.z);
                dstp[(sd+3)*20 + st] = us2f(vr.w);
            }
            if (t+2 < NT)
                vr = *(const ushort4*)(sp0 + (size_t)(tbase+(t+2)*16)*rstride);
        }
        #pragma unroll
        for (int jj = 0; jj < 16; jj += 4) {
            float4v dtq = *(const float4v*)&dtsT[cur][dl][jj];
            float4v xq  = *(const float4v*)&xsT [cur][dl][jj];
            float4v Bq  = *(const float4v*)&BshT[cur][s][jj];
            #pragma unroll
            for (int k = 0; k < 4; ++k) {
                float dtv = dtq[k];
                h = exp2f(dtv*A2)*h + (dtv*xq[k])*Bq[k];
                sdt += dtv;
            }
        }
        __syncthreads();
    }
    size_t o = ((size_t)c*nin + r)*256 + tid;
    hend [o] = h;
    Pprod[o] = exp2f(A2*sdt);
}

__global__ __launch_bounds__(256)
void scan_mid(const float* __restrict__ hend, const float* __restrict__ Pprod,
              float* __restrict__ hstart, int nin)
{
    int r = blockIdx.x, tid = threadIdx.x;
    float h = 0.f;
    hstart[(size_t)r*256 + tid] = 0.f;
    for (int c = 1; c < NCH; ++c) {
        size_t p = ((size_t)(c-1)*nin + r)*256 + tid;
        h = Pprod[p]*h + hend[p];
        hstart[((size_t)c*nin + r)*256 + tid] = h;
    }
}

__global__ __launch_bounds__(256)
void scan_pass2(const bf16* __restrict__ dt, const bf16* __restrict__ x,
                const bf16* __restrict__ dbc, const float* __restrict__ Alog,
                const float* __restrict__ Dpar, const float* __restrict__ hstart,
                bf16* __restrict__ y, int nin)
{
    __shared__ float dtsT[2][16][20], xsT[2][16][20], BshT[2][16][20], CshT[2][16][20];
    __shared__ bf16  ys[16][16];
    int c  = blockIdx.x / nin;
    int r  = blockIdx.x % nin;
    int b  = r / 96;
    int d0 = (r % 96) * 16;
    int tid = threadIdx.x;
    int s  = tid & 15;
    int dl = tid >> 4;
    int d  = d0 + dl;

    float A2 = -__expf(Alog[(size_t)d*DS + s]) * 1.44269504f;
    float Dv = Dpar[d];
    float h  = hstart[((size_t)c*nin + r)*256 + tid];

    int wv   = tid >> 6;
    int lane = tid & 63;
    int st = lane >> 2;
    int sd = (lane & 3) * 4;
    int tbase = c * CHUNK;
    const int NT = CHUNK/16;

    const unsigned short* sp0;
    size_t rstride;
    float* dst0;
    {
        size_t rb = (size_t)(b*SEQ + st);
        if (wv == 0)      { sp0 = (const unsigned short*)dt  + rb*DI + d0 + sd;       rstride = DI; dst0 = &dtsT[0][0][0]; }
        else if (wv == 1) { sp0 = (const unsigned short*)x   + rb*DI + d0 + sd;       rstride = DI; dst0 = &xsT[0][0][0]; }
        else if (wv == 2) { sp0 = (const unsigned short*)dbc + rb*80 + DTR + sd;      rstride = 80; dst0 = &BshT[0][0][0]; }
        else              { sp0 = (const unsigned short*)dbc + rb*80 + DTR + DS + sd; rstride = 80; dst0 = &CshT[0][0][0]; }
    }
    const size_t bufstride = 16*20;

    ushort4 vr = *(const ushort4*)(sp0 + (size_t)tbase*rstride);     // tile 0
    dst0[(sd+0)*20 + st] = us2f(vr.x);
    dst0[(sd+1)*20 + st] = us2f(vr.y);
    dst0[(sd+2)*20 + st] = us2f(vr.z);
    dst0[(sd+3)*20 + st] = us2f(vr.w);
    vr = *(const ushort4*)(sp0 + (size_t)(tbase+16)*rstride);        // tile 1
    __syncthreads();

    for (int t = 0; t < NT; ++t) {
        int cur = t & 1;
        if (t+1 < NT) {
            float* dstp = dst0 + (size_t)(cur^1)*bufstride;
            dstp[(sd+0)*20 + st] = us2f(vr.x);
            dstp[(sd+1)*20 + st] = us2f(vr.y);
            dstp[(sd+2)*20 + st] = us2f(vr.z);
            dstp[(sd+3)*20 + st] = us2f(vr.w);
        }
        if (t+2 < NT)
            vr = *(const ushort4*)(sp0 + (size_t)(tbase+(t+2)*16)*rstride);

        #pragma unroll
        for (int jj = 0; jj < 16; jj += 4) {
            float4v dtq = *(const float4v*)&dtsT[cur][dl][jj];
            float4v xq  = *(const float4v*)&xsT [cur][dl][jj];
            float4v Bq  = *(const float4v*)&BshT[cur][s][jj];
            float4v Cq  = *(const float4v*)&CshT[cur][s][jj];
            #pragma unroll
            for (int k = 0; k < 4; ++k) {
                float dtv = dtq[k];
                float xv  = xq[k];
                h = exp2f(dtv*A2)*h + (dtv*xv)*Bq[k];
                float p = h*Cq[k];
                p += __shfl_xor(p, 1, 16);
                p += __shfl_xor(p, 2, 16);
                p += __shfl_xor(p, 4, 16);
                p += __shfl_xor(p, 8, 16);
                if (s == 0) ys[jj+k][dl] = f2b(p + Dv*xv);
            }
        }
        __syncthreads();                 // ys ready + next buf staged
        if (wv == 0) {
            size_t rowm = (size_t)(b*SEQ + tbase + t*16 + st);
            ushort4 vy = *(const ushort4*)((const unsigned short*)&ys[st][0] + sd);
            *(ushort4*)((unsigned short*)y + rowm*DI + d0 + sd) = vy;
        }
        __syncthreads();                 // ys consumed
    }
}

// ---------------------------------------------------------------- LN(1536) * silu(z) gate
__global__ __launch_bounds__(256)
void gate_ln(const bf16* __restrict__ y, const bf16* __restrict__ z,
             const float* __restrict__ w, const float* __restrict__ bb,
             bf16* __restrict__ out)
{
    __shared__ float red[8];
    size_t t = blockIdx.x;
    const bf16* yy = y + t*DI;
    const bf16* zz = z + t*DI;
    float v[6]; float s = 0.f, s2 = 0.f;
    #pragma unroll
    for (int r = 0; r < 6; ++r) {
        v[r] = b2f(yy[threadIdx.x + 256*r]);
        s += v[r]; s2 += v[r]*v[r];
    }
    #pragma unroll
    for (int o = 32; o; o >>= 1) { s += __shfl_down(s, o, 64); s2 += __shfl_down(s2, o, 64); }
    if ((threadIdx.x & 63) == 0) { red[threadIdx.x >> 6] = s; red[(threadIdx.x >> 6) + 4] = s2; }
    __syncthreads();
    s  = red[0]+red[1]+red[2]+red[3];
    s2 = red[4]+red[5]+red[6]+red[7];
    float mu  = s * (1.f/DI);
    float inv = rsqrtf(fmaxf(s2*(1.f/DI) - mu*mu, 0.f) + 1e-5f);
    #pragma unroll
    for (int r = 0; r < 6; ++r) {
        int i = threadIdx.x + 256*r;
        float zv = b2f(zz[i]);
        float sig = 1.f/(1.f + __expf(-zv));
        out[t*DI + i] = f2b(((v[r]-mu)*inv*w[i] + bb[i]) * (zv*sig));
    }
}

// ---------------------------------------------------------------- mean pool over tokens
__global__ __launch_bounds__(256)
void pool_kernel(const bf16* __restrict__ hf, float* __restrict__ pooled)
{
    int idx = blockIdx.x*256 + threadIdx.x;   // < BATCH*DM
    int b = idx / DM, dm = idx % DM;
    const bf16* p = hf + (size_t)b*SEQ*DM + dm;
    float s = 0.f;
    for (int t = 0; t < SEQ; ++t) s += b2f(p[(size_t)t*DM]);
    pooled[idx] = s * (1.f/SEQ);
}

// ---------------------------------------------------------------- classifier head
__global__ __launch_bounds__(256)
void head_kernel(const unsigned* __restrict__ flag,
                 const float* __restrict__ pooled, const bf16* __restrict__ hw,
                 const float* __restrict__ hb, void* __restrict__ out)
{
    int idx = blockIdx.x*256 + threadIdx.x;
    if (idx >= BATCH*NCLS) return;
    int b = idx & 7, n = idx >> 3;
    const float* p = pooled + b*DM;
    const unsigned short* w = (const unsigned short*)hw + (size_t)n*DM;
    float acc = hb[n];
    for (int k = 0; k < DM; k += 4) {
        ushort4 wv = *(const ushort4*)(w + k);
        acc += p[k]*us2f(wv.x) + p[k+1]*us2f(wv.y) + p[k+2]*us2f(wv.z) + p[k+3]*us2f(wv.w);
    }
    int o = b*NCLS + n;
    if (flag[0]) ((float*)out)[o] = acc;
    else         ((bf16*)out)[o]  = f2b(acc);
}

// ================================================================ launcher
extern "C" void kernel_launch(void* const* d_in, const int* in_sizes, int n_in,
                              void* d_out, int out_size, void* d_ws, size_t ws_size,
                              hipStream_t stream)
{
    (void)n_in; (void)out_size;
    dim3 blk(256);

    const bool is_f32[21] = { false, false, true, true, true, true, false, true, true,
                              false, false, true,  true, true, true, true, false,
                              true,  true,  false, true };

    size_t off = 0;
    auto carve = [&](size_t bytes) -> void* {
        void* q = (char*)d_ws + off;
        off += (bytes + 255) & ~(size_t)255;
        return q;
    };

    unsigned* flag = (unsigned*)carve(256);
    void* canon[21];
    for (int i = 0; i < 21; ++i)
        canon[i] = carve((size_t)in_sizes[i] * (is_f32[i] ? 4 : 2));

    float* residual = (float*)carve((size_t)M_TOK*DM*4);
    bf16*  hn       = (bf16*) carve((size_t)M_TOK*DM*2);
    float* pooled   = (float*)carve((size_t)BATCH*DM*4);

    const size_t scanbuf1 = (size_t)NCH*96*256*4;   // per g-unit, per array (1.31 MB)
    const size_t inner1 = 4*(((size_t)SEQ*DI*2 + 255) & ~(size_t)255)
                          + (((size_t)SEQ*80*2 + 255) & ~(size_t)255)
                          + 3*((scanbuf1 + 255) & ~(size_t)255);
    int g = 8;
    while (g > 1 && off + (size_t)g*inner1 > ws_size) g >>= 1;

    bf16* xh  = (bf16*)carve((size_t)g*SEQ*DI*2);   // also Ap / ybuf
    bf16* zh  = (bf16*)carve((size_t)g*SEQ*DI*2);
    bf16* xc  = (bf16*)carve((size_t)g*SEQ*DI*2);
    bf16* dtb = (bf16*)carve((size_t)g*SEQ*DI*2);   // also gated
    bf16* dbc = (bf16*)carve((size_t)g*SEQ*80*2);
    float* hend   = (float*)carve((size_t)g*scanbuf1);
    float* Pprod  = (float*)carve((size_t)g*scanbuf1);
    float* hstart = (float*)carve((size_t)g*scanbuf1);
    bf16* Ap    = xh;
    bf16* ybuf  = xh;
    bf16* gated = dtb;

    detect_dtype<<<1, 64, 0, stream>>>((const unsigned short*)d_in[4], flag);
    for (int i = 0; i < 21; ++i) {
        int n = in_sizes[i];
        int gr = (n + 255)/256;
        if (is_f32[i]) to_f32 <<<gr, blk, 0, stream>>>(flag, d_in[i], (float*)canon[i], n);
        else           to_bf16<<<gr, blk, 0, stream>>>(flag, d_in[i], (bf16*) canon[i], n);
    }

    const bf16*  xin   = (const bf16*) canon[0];
    const bf16*  pw    = (const bf16*) canon[1];
    const float* pb    = (const float*)canon[2];
    const float* chan  = (const float*)canon[3];
    const float* nw    = (const float*)canon[4];
    const float* nb    = (const float*)canon[5];
    const bf16*  ipw   = (const bf16*) canon[6];
    const float* cw    = (const float*)canon[7];
    const float* cb    = (const float*)canon[8];
    const bf16*  xpw   = (const bf16*) canon[9];
    const bf16*  dtw   = (const bf16*) canon[10];
    const float* dtbia = (const float*)canon[11];
    const float* Alog  = (const float*)canon[12];
    const float* Dpar  = (const float*)canon[13];
    const float* snw   = (const float*)canon[14];
    const float* snb   = (const float*)canon[15];
    const bf16*  opw   = (const bf16*) canon[16];
    const float* nfw   = (const float*)canon[17];
    const float* nfb   = (const float*)canon[18];
    const bf16*  hw    = (const bf16*) canon[19];
    const float* hb    = (const float*)canon[20];

    const int MG  = g*SEQ;
    const int GXm = (MG + 127)/128;       // MFMA grid (M)
    const int nin = g*96;                 // scan inner blocks per chunk

    // dispatch helper: fast path when all dims are tile-clean
    auto launch_gemm = [&](const bf16* A, int lda, const bf16* W, int ldw,
                           float* Cf, bf16* Cb, int ldc,
                           const float* bias, const float* chan_,
                           int M, int N, int K, int epi) {
        dim3 gr((M + 127)/128, (N + 127)/128);
        if ((M & 127) == 0 && (N & 127) == 0 && (K & 31) == 0)
            gemm_mfma_fast<<<gr, blk, 0, stream>>>(A, lda, W, ldw, Cf, Cb, ldc,
                                                   bias, chan_, N, K, epi);
        else
            gemm_mfma<<<gr, blk, 0, stream>>>(A, lda, W, ldw, Cf, Cb, ldc,
                                              bias, chan_, M, N, K, epi);
    };

    // ---- patch embed -> residual (fp32), MFMA epi3 ----
    for (int b0 = 0; b0 < BATCH; b0 += g) {
        gather_patches<<<MG, blk, 0, stream>>>(xin, Ap, b0);
        launch_gemm(Ap, 256, pw, 256,
                    residual + (size_t)b0*SEQ*DM, nullptr, DM,
                    pb, chan, MG, DM, 256, 3);
    }

    for (int l = 0; l < LAYERS; ++l) {
        ln768<<<M_TOK, blk, 0, stream>>>(residual, nw + l*DM, nb + l*DM, hn);
        for (int b0 = 0; b0 < BATCH; b0 += g) {
            const bf16* hng = hn + (size_t)b0*SEQ*DM;
            // in_proj halves (MFMA)
            launch_gemm(hng, DM, ipw + (size_t)l*2*DI*DM, DM,
                        nullptr, xh, DI, nullptr, nullptr, MG, DI, DM, 0);
            launch_gemm(hng, DM, ipw + (size_t)l*2*DI*DM + (size_t)DI*DM, DM,
                        nullptr, zh, DI, nullptr, nullptr, MG, DI, DM, 0);
            conv_silu<<<(MG*DI)/256, blk, 0, stream>>>(xh, cw + (size_t)l*DI*4, cb + l*DI, xc);
            // x_proj (N=80, ragged -> slow path)
            launch_gemm(xc, DI, xpw + (size_t)l*80*DI, DI,
                        nullptr, dbc, 80, nullptr, nullptr, MG, 80, DI, 0);
            // dt_proj + softplus (K=48, ragged -> slow path)
            launch_gemm(dbc, 80, dtw + (size_t)l*DI*DTR, DTR,
                        nullptr, dtb, DI, dtbia + l*DI, nullptr, MG, DI, DTR, 1);
            scan_pass1<<<(NCH-1)*nin, blk, 0, stream>>>(dtb, xc, dbc,
                                                        Alog + (size_t)l*DI*DS,
                                                        hend, Pprod, nin);
            scan_mid<<<nin, blk, 0, stream>>>(hend, Pprod, hstart, nin);
            scan_pass2<<<NCH*nin, blk, 0, stream>>>(dtb, xc, dbc,
                                                    Alog + (size_t)l*DI*DS,
                                                    Dpar + l*DI, hstart, ybuf, nin);
            gate_ln<<<MG, blk, 0, stream>>>(ybuf, zh, snw + l*DI, snb + l*DI, gated);
            // out_proj += residual (MFMA epi2)
            launch_gemm(gated, DI, opw + (size_t)l*DM*DI, DI,
                        residual + (size_t)b0*SEQ*DM, nullptr, DM,
                        nullptr, nullptr, MG, DM, DI, 2);
        }
    }

    ln768<<<M_TOK, blk, 0, stream>>>(residual, nfw, nfb, hn);
    pool_kernel<<<(BATCH*DM)/256, blk, 0, stream>>>(hn, pooled);
    head_kernel<<<(BATCH*NCLS + 255)/256, blk, 0, stream>>>(flag, pooled, hw, hb, d_out);
}

// Round 6
// 3957.418 us; speedup vs baseline: 1.2436x; 1.1587x over previous
//
#include <hip/hip_runtime.h>
#include <hip/hip_bf16.h>

typedef __hip_bfloat16 bf16;
typedef __attribute__((ext_vector_type(8))) short short8;
typedef __attribute__((ext_vector_type(4))) float float4v;

#define BATCH 8
#define SEQ   1568            // 14*14*8 tokens per batch
#define M_TOK (BATCH*SEQ)     // 12544
#define DM    768
#define DI    1536
#define DS    16
#define DTR   48
#define NCLS  1000
#define LAYERS 4
#define CHUNK 112             // scan chunk length (7 tiles of 16)
#define NCH   14              // SEQ / CHUNK

__device__ __forceinline__ float b2f(bf16 v){ return __bfloat162float(v); }
__device__ __forceinline__ bf16  f2b(float v){ return __float2bfloat16(v); }
__device__ __forceinline__ float us2f(unsigned short u){
    unsigned v = ((unsigned)u) << 16; float f; __builtin_memcpy(&f, &v, 4); return f;
}
// async global->LDS, 16B per lane; LDS dest = uniform base + lane*16
__device__ __forceinline__ void gload_lds16(const void* g, void* l){
    __builtin_amdgcn_global_load_lds(
        (const __attribute__((address_space(1))) void*)g,
        (__attribute__((address_space(3))) void*)l, 16, 0, 0);
}
// VALU-pipe cross-lane add via DPP (keeps reduction off the shared DS pipe).
// CTRL must be an immediate: template parameter.
// 0xB1 quad_perm xor1, 0x4E quad_perm xor2, 0x124 row_ror:4, 0x128 row_ror:8
template<int CTRL>
__device__ __forceinline__ float dpp_add(float p){
    int pi; __builtin_memcpy(&pi, &p, 4);
    int mi = __builtin_amdgcn_update_dpp(pi, pi, CTRL, 0xF, 0xF, false);
    float m; __builtin_memcpy(&m, &mi, 4);
    return p + m;
}

// ---------------------------------------------------------------- dtype probe
__global__ void detect_dtype(const unsigned short* __restrict__ probe, unsigned* __restrict__ flag)
{
    if (threadIdx.x == 0 && blockIdx.x == 0) flag[0] = (probe[0] == 0) ? 1u : 0u;  // 1 = fp32
}

__global__ __launch_bounds__(256)
void to_bf16(const unsigned* __restrict__ flag, const void* __restrict__ src,
             bf16* __restrict__ dst, int n)
{
    int i = blockIdx.x*256 + threadIdx.x;
    if (i >= n) return;
    dst[i] = flag[0] ? f2b(((const float*)src)[i]) : ((const bf16*)src)[i];
}

__global__ __launch_bounds__(256)
void to_f32(const unsigned* __restrict__ flag, const void* __restrict__ src,
            float* __restrict__ dst, int n)
{
    int i = blockIdx.x*256 + threadIdx.x;
    if (i >= n) return;
    dst[i] = flag[0] ? ((const float*)src)[i] : b2f(((const bf16*)src)[i]);
}

// ---------------------------------------------------------------- gather patches (per batch-group)
__global__ __launch_bounds__(256)
void gather_patches(const bf16* __restrict__ x, bf16* __restrict__ Ap, int b0)
{
    size_t idx = (size_t)blockIdx.x*256 + threadIdx.x;
    int i = (int)(idx & 255);
    int m = (int)(idx >> 8);
    int b = b0 + m / SEQ, s = m % SEQ;
    int hw = s >> 3, c = s & 7;
    int h = hw / 14, w = hw % 14;
    int p = i >> 4, q = i & 15;
    Ap[idx] = x[(((size_t)(b*8 + c)*224) + h*16 + p)*224 + w*16 + q];
}

// ---------------------------------------------------------------- MFMA GEMM, ragged-safe (128x128, BK=32)
// C[m,n] = sum_k A[m,k]*W[n,k]; guards on M/N rows + K 8-chunks.
// epi 0: Cb=bf16(acc); epi 1: Cb=bf16(softplus(acc+bias[n])); epi 2: Cf+=acc;
// epi 3: Cf=acc+bias[n]+chan[(m&7)*N+n]
__global__ __launch_bounds__(256)
void gemm_mfma(const bf16* __restrict__ A, int lda,
               const bf16* __restrict__ W, int ldw,
               float* __restrict__ Cf, bf16* __restrict__ Cb, int ldc,
               const float* __restrict__ bias, const float* __restrict__ chan,
               int M, int N, int K, int epi)
{
    __shared__ short As[128*40];   // 32 + 8 pad elems per row (80B stride, 16B aligned)
    __shared__ short Bs[128*40];
    int tid  = threadIdx.x;
    int m0   = blockIdx.x*128, n0 = blockIdx.y*128;
    int lane = tid & 63, wv = tid >> 6;
    int wm = (wv >> 1)*64, wn = (wv & 1)*64;
    int l15 = lane & 15, quad = lane >> 4;

    float4v acc[4][4];
    #pragma unroll
    for (int i = 0; i < 4; ++i)
        #pragma unroll
        for (int j = 0; j < 4; ++j) acc[i][j] = (float4v){0.f,0.f,0.f,0.f};

    const short8 zv8 = {0,0,0,0,0,0,0,0};
    for (int k0 = 0; k0 < K; k0 += 32) {
        #pragma unroll
        for (int u = 0; u < 2; ++u) {
            int c   = tid*2 + u;           // 512 chunks of 16B
            int row = c >> 2, ch = c & 3;
            bool kok = (k0 + ch*8 + 8) <= K;   // K is a multiple of 8
            short8 va = (kok && m0 + row < M)
                ? *(const short8*)((const short*)A + (size_t)(m0+row)*lda + k0 + ch*8) : zv8;
            *(short8*)(As + row*40 + ch*8) = va;
            short8 vb = (kok && n0 + row < N)
                ? *(const short8*)((const short*)W + (size_t)(n0+row)*ldw + k0 + ch*8) : zv8;
            *(short8*)(Bs + row*40 + ch*8) = vb;
        }
        __syncthreads();
        short8 av[4], bv[4];
        #pragma unroll
        for (int i = 0; i < 4; ++i) av[i] = *(const short8*)(As + (wm + i*16 + l15)*40 + quad*8);
        #pragma unroll
        for (int j = 0; j < 4; ++j) bv[j] = *(const short8*)(Bs + (wn + j*16 + l15)*40 + quad*8);
        #pragma unroll
        for (int i = 0; i < 4; ++i)
            #pragma unroll
            for (int j = 0; j < 4; ++j)
                acc[i][j] = __builtin_amdgcn_mfma_f32_16x16x32_bf16(av[i], bv[j], acc[i][j], 0, 0, 0);
        __syncthreads();
    }

    // C/D layout: col = lane&15, row = quad*4 + reg
    #pragma unroll
    for (int i = 0; i < 4; ++i) {
        #pragma unroll
        for (int j = 0; j < 4; ++j) {
            int gn = n0 + wn + j*16 + l15;
            if (gn >= N) continue;
            #pragma unroll
            for (int r = 0; r < 4; ++r) {
                int gm = m0 + wm + i*16 + quad*4 + r;
                if (gm >= M) continue;
                float v = acc[i][j][r];
                size_t off = (size_t)gm*ldc + gn;
                if (epi == 0)      Cb[off] = f2b(v);
                else if (epi == 1) {
                    v += bias[gn];
                    v = (v > 20.f) ? v : log1pf(__expf(v));
                    Cb[off] = f2b(v);
                }
                else if (epi == 2) Cf[off] += v;
                else               Cf[off] = v + bias[gn] + chan[(size_t)(gm & 7)*N + gn];
            }
        }
    }
}

// ---------------------------------------------------------------- MFMA GEMM fast path (m97 recipe)
// Requires M%128==0, N%128==0, K%32==0. Linear [128][32] LDS (64B rows),
// staged via global_load_lds dwordx4.
__global__ __launch_bounds__(256)
void gemm_mfma_fast(const bf16* __restrict__ A, int lda,
                    const bf16* __restrict__ W, int ldw,
                    float* __restrict__ Cf, bf16* __restrict__ Cb, int ldc,
                    const float* __restrict__ bias, const float* __restrict__ chan,
                    int N, int K, int epi)
{
    __shared__ short As[128*32];
    __shared__ short Bs[128*32];
    int tid  = threadIdx.x;
    int m0   = blockIdx.x*128, n0 = blockIdx.y*128;
    int lane = tid & 63, wv = tid >> 6;
    int wm = (wv >> 1)*64, wn = (wv & 1)*64;
    int l15 = lane & 15, quad = lane >> 4;

    int srow = (lane >> 2);          // row within 16-row chunk
    int skof = (lane & 3) * 8;       // k element offset within row

    float4v acc[4][4];
    #pragma unroll
    for (int i = 0; i < 4; ++i)
        #pragma unroll
        for (int j = 0; j < 4; ++j) acc[i][j] = (float4v){0.f,0.f,0.f,0.f};

    const short* Ab = (const short*)A;
    const short* Wb = (const short*)W;

    for (int k0 = 0; k0 < K; k0 += 32) {
        #pragma unroll
        for (int u = 0; u < 2; ++u) {
            int c = wv*2 + u;                 // chunk 0..7
            int row = c*16 + srow;
            gload_lds16(Ab + (size_t)(m0+row)*lda + k0 + skof, As + c*512);
            gload_lds16(Wb + (size_t)(n0+row)*ldw + k0 + skof, Bs + c*512);
        }
        __syncthreads();                       // drains vmcnt (compiler-inserted)
        short8 av[4], bv[4];
        #pragma unroll
        for (int i = 0; i < 4; ++i) av[i] = *(const short8*)(As + (wm + i*16 + l15)*32 + quad*8);
        #pragma unroll
        for (int j = 0; j < 4; ++j) bv[j] = *(const short8*)(Bs + (wn + j*16 + l15)*32 + quad*8);
        #pragma unroll
        for (int i = 0; i < 4; ++i)
            #pragma unroll
            for (int j = 0; j < 4; ++j)
                acc[i][j] = __builtin_amdgcn_mfma_f32_16x16x32_bf16(av[i], bv[j], acc[i][j], 0, 0, 0);
        __syncthreads();
    }

    #pragma unroll
    for (int i = 0; i < 4; ++i) {
        #pragma unroll
        for (int j = 0; j < 4; ++j) {
            int gn = n0 + wn + j*16 + l15;
            #pragma unroll
            for (int r = 0; r < 4; ++r) {
                int gm = m0 + wm + i*16 + quad*4 + r;
                float v = acc[i][j][r];
                size_t off = (size_t)gm*ldc + gn;
                if (epi == 0)      Cb[off] = f2b(v);
                else if (epi == 1) {
                    v += bias[gn];
                    v = (v > 20.f) ? v : log1pf(__expf(v));
                    Cb[off] = f2b(v);
                }
                else if (epi == 2) Cf[off] += v;
                else               Cf[off] = v + bias[gn] + chan[(size_t)(gm & 7)*N + gn];
            }
        }
    }
}

// ---------------------------------------------------------------- LayerNorm 768 (fp32 in, bf16 out)
__global__ __launch_bounds__(256)
void ln768(const float* __restrict__ X, const float* __restrict__ w,
           const float* __restrict__ bb, bf16* __restrict__ out)
{
    __shared__ float red[8];
    size_t t = blockIdx.x;
    const float* x = X + t*DM;
    float v[3]; float s = 0.f, s2 = 0.f;
    #pragma unroll
    for (int r = 0; r < 3; ++r) {
        v[r] = x[threadIdx.x + 256*r];
        s += v[r]; s2 += v[r]*v[r];
    }
    #pragma unroll
    for (int o = 32; o; o >>= 1) { s += __shfl_down(s, o, 64); s2 += __shfl_down(s2, o, 64); }
    if ((threadIdx.x & 63) == 0) { red[threadIdx.x >> 6] = s; red[(threadIdx.x >> 6) + 4] = s2; }
    __syncthreads();
    s  = red[0]+red[1]+red[2]+red[3];
    s2 = red[4]+red[5]+red[6]+red[7];
    float mu  = s * (1.f/DM);
    float inv = rsqrtf(fmaxf(s2*(1.f/DM) - mu*mu, 0.f) + 1e-5f);
    #pragma unroll
    for (int r = 0; r < 3; ++r) {
        int i = threadIdx.x + 256*r;
        out[t*DM + i] = f2b((v[r]-mu)*inv*w[i] + bb[i]);
    }
}

// ---------------------------------------------------------------- causal depthwise conv (k=4) + silu
// vectorized: 8 d per thread, short8 loads/stores (G13)
__global__ __launch_bounds__(256)
void conv_silu(const bf16* __restrict__ xh, const float* __restrict__ cw,
               const float* __restrict__ cb, bf16* __restrict__ xc)
{
    size_t idx = (size_t)blockIdx.x*256 + threadIdx.x;   // < g*SEQ*DI/8
    int dv = (int)(idx % (DI/8));
    int m  = (int)(idx / (DI/8));
    int b = m / SEQ, t = m % SEQ;                        // local batch
    int d = dv*8;

    float4v cwq[8];
    #pragma unroll
    for (int j = 0; j < 8; ++j) cwq[j] = *(const float4v*)(cw + (size_t)(d+j)*4);

    float acc[8];
    #pragma unroll
    for (int j = 0; j < 8; ++j) acc[j] = cb[d+j];

    #pragma unroll
    for (int k = 0; k < 4; ++k) {
        int tt = t + k - 3;
        if (tt >= 0) {
            short8 v = *(const short8*)((const short*)xh + (size_t)(b*SEQ + tt)*DI + d);
            #pragma unroll
            for (int j = 0; j < 8; ++j)
                acc[j] += us2f((unsigned short)v[j]) * cwq[j][k];
        }
    }
    short8 o;
    #pragma unroll
    for (int j = 0; j < 8; ++j) {
        float sig = 1.f/(1.f + __expf(-acc[j]));
        bf16 r = f2b(acc[j]*sig);
        unsigned short u; __builtin_memcpy(&u, &r, 2); o[j] = (short)u;
    }
    *(short8*)((short*)xc + idx*8) = o;
}

// ---------------------------------------------------------------- selective scan: chunked 2-pass,
// double-buffered staging; pass2 state-reduction on VALU via DPP (not DS pipe).

__global__ __launch_bounds__(256)
void scan_pass1(const bf16* __restrict__ dt, const bf16* __restrict__ x,
                const bf16* __restrict__ dbc, const float* __restrict__ Alog,
                float* __restrict__ hend, float* __restrict__ Pprod, int nin)
{
    __shared__ float dtsT[2][16][20], xsT[2][16][20], BshT[2][16][20];
    int c  = blockIdx.x / nin;          // chunk 0..NCH-2
    int r  = blockIdx.x % nin;
    int b  = r / 96;
    int d0 = (r % 96) * 16;
    int tid = threadIdx.x;
    int s  = tid & 15;
    int dl = tid >> 4;
    int d  = d0 + dl;

    float A2 = -__expf(Alog[(size_t)d*DS + s]) * 1.44269504f;
    float h = 0.f, sdt = 0.f;

    int wv   = tid >> 6;
    int lane = tid & 63;
    int st = lane >> 2;      // staging timestep 0..15
    int sd = (lane & 3) * 4; // staging inner offset {0,4,8,12}
    int tbase = c * CHUNK;
    const int NT = CHUNK/16; // 7

    const unsigned short* sp0 = nullptr;
    size_t rstride = 0;
    float* dst0 = nullptr;
    {
        size_t rb = (size_t)(b*SEQ + st);
        if (wv == 0)      { sp0 = (const unsigned short*)dt  + rb*DI + d0 + sd; rstride = DI; dst0 = &dtsT[0][0][0]; }
        else if (wv == 1) { sp0 = (const unsigned short*)x   + rb*DI + d0 + sd; rstride = DI; dst0 = &xsT[0][0][0]; }
        else if (wv == 2) { sp0 = (const unsigned short*)dbc + rb*80 + DTR + sd; rstride = 80; dst0 = &BshT[0][0][0]; }
    }
    const size_t bufstride = 16*20;     // floats between buf0 and buf1

    ushort4 vr;
    if (wv < 3) {
        vr = *(const ushort4*)(sp0 + (size_t)tbase*rstride);        // tile 0
        dst0[(sd+0)*20 + st] = us2f(vr.x);
        dst0[(sd+1)*20 + st] = us2f(vr.y);
        dst0[(sd+2)*20 + st] = us2f(vr.z);
        dst0[(sd+3)*20 + st] = us2f(vr.w);
        vr = *(const ushort4*)(sp0 + (size_t)(tbase+16)*rstride);   // tile 1
    }
    __syncthreads();

    for (int t = 0; t < NT; ++t) {
        int cur = t & 1;
        if (wv < 3) {
            if (t+1 < NT) {
                float* dstp = dst0 + (size_t)(cur^1)*bufstride;
                dstp[(sd+0)*20 + st] = us2f(vr.x);
                dstp[(sd+1)*20 + st] = us2f(vr.y);
                dstp[(sd+2)*20 + st] = us2f(vr.z);
                dstp[(sd+3)*20 + st] = us2f(vr.w);
            }
            if (t+2 < NT)
                vr = *(const ushort4*)(sp0 + (size_t)(tbase+(t+2)*16)*rstride);
        }
        #pragma unroll
        for (int jj = 0; jj < 16; jj += 4) {
            float4v dtq = *(const float4v*)&dtsT[cur][dl][jj];
            float4v xq  = *(const float4v*)&xsT [cur][dl][jj];
            float4v Bq  = *(const float4v*)&BshT[cur][s][jj];
            #pragma unroll
            for (int k = 0; k < 4; ++k) {
                float dtv = dtq[k];
                h = exp2f(dtv*A2)*h + (dtv*xq[k])*Bq[k];
                sdt += dtv;
            }
        }
        __syncthreads();
    }
    size_t o = ((size_t)c*nin + r)*256 + tid;
    hend [o] = h;
    Pprod[o] = exp2f(A2*sdt);
}

__global__ __launch_bounds__(256)
void scan_mid(const float* __restrict__ hend, const float* __restrict__ Pprod,
              float* __restrict__ hstart, int nin)
{
    int r = blockIdx.x, tid = threadIdx.x;
    float h = 0.f;
    hstart[(size_t)r*256 + tid] = 0.f;
    for (int c = 1; c < NCH; ++c) {
        size_t p = ((size_t)(c-1)*nin + r)*256 + tid;
        h = Pprod[p]*h + hend[p];
        hstart[((size_t)c*nin + r)*256 + tid] = h;
    }
}

__global__ __launch_bounds__(256)
void scan_pass2(const bf16* __restrict__ dt, const bf16* __restrict__ x,
                const bf16* __restrict__ dbc, const float* __restrict__ Alog,
                const float* __restrict__ Dpar, const float* __restrict__ hstart,
                bf16* __restrict__ y, int nin)
{
    __shared__ float dtsT[2][16][20], xsT[2][16][20], BshT[2][16][20], CshT[2][16][20];
    __shared__ bf16  ys[16][16];
    int c  = blockIdx.x / nin;
    int r  = blockIdx.x % nin;
    int b  = r / 96;
    int d0 = (r % 96) * 16;
    int tid = threadIdx.x;
    int s  = tid & 15;
    int dl = tid >> 4;
    int d  = d0 + dl;

    float A2 = -__expf(Alog[(size_t)d*DS + s]) * 1.44269504f;
    float Dv = Dpar[d];
    float h  = hstart[((size_t)c*nin + r)*256 + tid];

    int wv   = tid >> 6;
    int lane = tid & 63;
    int st = lane >> 2;
    int sd = (lane & 3) * 4;
    int tbase = c * CHUNK;
    const int NT = CHUNK/16;

    const unsigned short* sp0;
    size_t rstride;
    float* dst0;
    {
        size_t rb = (size_t)(b*SEQ + st);
        if (wv == 0)      { sp0 = (const unsigned short*)dt  + rb*DI + d0 + sd;       rstride = DI; dst0 = &dtsT[0][0][0]; }
        else if (wv == 1) { sp0 = (const unsigned short*)x   + rb*DI + d0 + sd;       rstride = DI; dst0 = &xsT[0][0][0]; }
        else if (wv == 2) { sp0 = (const unsigned short*)dbc + rb*80 + DTR + sd;      rstride = 80; dst0 = &BshT[0][0][0]; }
        else              { sp0 = (const unsigned short*)dbc + rb*80 + DTR + DS + sd; rstride = 80; dst0 = &CshT[0][0][0]; }
    }
    const size_t bufstride = 16*20;

    ushort4 vr = *(const ushort4*)(sp0 + (size_t)tbase*rstride);     // tile 0
    dst0[(sd+0)*20 + st] = us2f(vr.x);
    dst0[(sd+1)*20 + st] = us2f(vr.y);
    dst0[(sd+2)*20 + st] = us2f(vr.z);
    dst0[(sd+3)*20 + st] = us2f(vr.w);
    vr = *(const ushort4*)(sp0 + (size_t)(tbase+16)*rstride);        // tile 1
    __syncthreads();

    for (int t = 0; t < NT; ++t) {
        int cur = t & 1;
        if (t+1 < NT) {
            float* dstp = dst0 + (size_t)(cur^1)*bufstride;
            dstp[(sd+0)*20 + st] = us2f(vr.x);
            dstp[(sd+1)*20 + st] = us2f(vr.y);
            dstp[(sd+2)*20 + st] = us2f(vr.z);
            dstp[(sd+3)*20 + st] = us2f(vr.w);
        }
        if (t+2 < NT)
            vr = *(const ushort4*)(sp0 + (size_t)(tbase+(t+2)*16)*rstride);

        #pragma unroll
        for (int jj = 0; jj < 16; jj += 4) {
            float4v dtq = *(const float4v*)&dtsT[cur][dl][jj];
            float4v xq  = *(const float4v*)&xsT [cur][dl][jj];
            float4v Bq  = *(const float4v*)&BshT[cur][s][jj];
            float4v Cq  = *(const float4v*)&CshT[cur][s][jj];
            #pragma unroll
            for (int k = 0; k < 4; ++k) {
                float dtv = dtq[k];
                float xv  = xq[k];
                h = exp2f(dtv*A2)*h + (dtv*xv)*Bq[k];
                float p = h*Cq[k];
                // 16-lane sum on the VALU pipe (DPP), not DS: after quad
                // butterfly all quad lanes equal -> ror4/ror8 finish the sum;
                // every lane ends with the full 16-state total.
                p = dpp_add<0xB1>(p);    // quad_perm xor1
                p = dpp_add<0x4E>(p);    // quad_perm xor2
                p = dpp_add<0x124>(p);   // row_ror:4
                p = dpp_add<0x128>(p);   // row_ror:8
                if (s == 0) ys[jj+k][dl] = f2b(p + Dv*xv);
            }
        }
        __syncthreads();                 // ys ready + next buf staged
        if (wv == 0) {
            size_t rowm = (size_t)(b*SEQ + tbase + t*16 + st);
            ushort4 vy = *(const ushort4*)((const unsigned short*)&ys[st][0] + sd);
            *(ushort4*)((unsigned short*)y + rowm*DI + d0 + sd) = vy;
        }
        __syncthreads();                 // ys consumed
    }
}

// ---------------------------------------------------------------- LN(1536) * silu(z) gate
__global__ __launch_bounds__(256)
void gate_ln(const bf16* __restrict__ y, const bf16* __restrict__ z,
             const float* __restrict__ w, const float* __restrict__ bb,
             bf16* __restrict__ out)
{
    __shared__ float red[8];
    size_t t = blockIdx.x;
    const bf16* yy = y + t*DI;
    const bf16* zz = z + t*DI;
    float v[6]; float s = 0.f, s2 = 0.f;
    #pragma unroll
    for (int r = 0; r < 6; ++r) {
        v[r] = b2f(yy[threadIdx.x + 256*r]);
        s += v[r]; s2 += v[r]*v[r];
    }
    #pragma unroll
    for (int o = 32; o; o >>= 1) { s += __shfl_down(s, o, 64); s2 += __shfl_down(s2, o, 64); }
    if ((threadIdx.x & 63) == 0) { red[threadIdx.x >> 6] = s; red[(threadIdx.x >> 6) + 4] = s2; }
    __syncthreads();
    s  = red[0]+red[1]+red[2]+red[3];
    s2 = red[4]+red[5]+red[6]+red[7];
    float mu  = s * (1.f/DI);
    float inv = rsqrtf(fmaxf(s2*(1.f/DI) - mu*mu, 0.f) + 1e-5f);
    #pragma unroll
    for (int r = 0; r < 6; ++r) {
        int i = threadIdx.x + 256*r;
        float zv = b2f(zz[i]);
        float sig = 1.f/(1.f + __expf(-zv));
        out[t*DI + i] = f2b(((v[r]-mu)*inv*w[i] + bb[i]) * (zv*sig));
    }
}

// ---------------------------------------------------------------- mean pool over tokens
__global__ __launch_bounds__(256)
void pool_kernel(const bf16* __restrict__ hf, float* __restrict__ pooled)
{
    int idx = blockIdx.x*256 + threadIdx.x;   // < BATCH*DM
    int b = idx / DM, dm = idx % DM;
    const bf16* p = hf + (size_t)b*SEQ*DM + dm;
    float s = 0.f;
    for (int t = 0; t < SEQ; ++t) s += b2f(p[(size_t)t*DM]);
    pooled[idx] = s * (1.f/SEQ);
}

// ---------------------------------------------------------------- classifier head
__global__ __launch_bounds__(256)
void head_kernel(const unsigned* __restrict__ flag,
                 const float* __restrict__ pooled, const bf16* __restrict__ hw,
                 const float* __restrict__ hb, void* __restrict__ out)
{
    int idx = blockIdx.x*256 + threadIdx.x;
    if (idx >= BATCH*NCLS) return;
    int b = idx & 7, n = idx >> 3;
    const float* p = pooled + b*DM;
    const unsigned short* w = (const unsigned short*)hw + (size_t)n*DM;
    float acc = hb[n];
    for (int k = 0; k < DM; k += 4) {
        ushort4 wv = *(const ushort4*)(w + k);
        acc += p[k]*us2f(wv.x) + p[k+1]*us2f(wv.y) + p[k+2]*us2f(wv.z) + p[k+3]*us2f(wv.w);
    }
    int o = b*NCLS + n;
    if (flag[0]) ((float*)out)[o] = acc;
    else         ((bf16*)out)[o]  = f2b(acc);
}

// ================================================================ launcher
extern "C" void kernel_launch(void* const* d_in, const int* in_sizes, int n_in,
                              void* d_out, int out_size, void* d_ws, size_t ws_size,
                              hipStream_t stream)
{
    (void)n_in; (void)out_size;
    dim3 blk(256);

    const bool is_f32[21] = { false, false, true, true, true, true, false, true, true,
                              false, false, true,  true, true, true, true, false,
                              true,  true,  false, true };

    size_t off = 0;
    auto carve = [&](size_t bytes) -> void* {
        void* q = (char*)d_ws + off;
        off += (bytes + 255) & ~(size_t)255;
        return q;
    };

    unsigned* flag = (unsigned*)carve(256);
    void* canon[21];
    for (int i = 0; i < 21; ++i)
        canon[i] = carve((size_t)in_sizes[i] * (is_f32[i] ? 4 : 2));

    float* residual = (float*)carve((size_t)M_TOK*DM*4);
    bf16*  hn       = (bf16*) carve((size_t)M_TOK*DM*2);
    float* pooled   = (float*)carve((size_t)BATCH*DM*4);

    const size_t scanbuf1 = (size_t)NCH*96*256*4;   // per g-unit, per array (1.31 MB)
    const size_t inner1 = 4*(((size_t)SEQ*DI*2 + 255) & ~(size_t)255)
                          + (((size_t)SEQ*80*2 + 255) & ~(size_t)255)
                          + 3*((scanbuf1 + 255) & ~(size_t)255);
    int g = 8;
    while (g > 1 && off + (size_t)g*inner1 > ws_size) g >>= 1;

    bf16* xh  = (bf16*)carve((size_t)g*SEQ*DI*2);   // also Ap / ybuf
    bf16* zh  = (bf16*)carve((size_t)g*SEQ*DI*2);
    bf16* xc  = (bf16*)carve((size_t)g*SEQ*DI*2);
    bf16* dtb = (bf16*)carve((size_t)g*SEQ*DI*2);   // also gated
    bf16* dbc = (bf16*)carve((size_t)g*SEQ*80*2);
    float* hend   = (float*)carve((size_t)g*scanbuf1);
    float* Pprod  = (float*)carve((size_t)g*scanbuf1);
    float* hstart = (float*)carve((size_t)g*scanbuf1);
    bf16* Ap    = xh;
    bf16* ybuf  = xh;
    bf16* gated = dtb;

    detect_dtype<<<1, 64, 0, stream>>>((const unsigned short*)d_in[4], flag);
    for (int i = 0; i < 21; ++i) {
        int n = in_sizes[i];
        int gr = (n + 255)/256;
        if (is_f32[i]) to_f32 <<<gr, blk, 0, stream>>>(flag, d_in[i], (float*)canon[i], n);
        else           to_bf16<<<gr, blk, 0, stream>>>(flag, d_in[i], (bf16*) canon[i], n);
    }

    const bf16*  xin   = (const bf16*) canon[0];
    const bf16*  pw    = (const bf16*) canon[1];
    const float* pb    = (const float*)canon[2];
    const float* chan  = (const float*)canon[3];
    const float* nw    = (const float*)canon[4];
    const float* nb    = (const float*)canon[5];
    const bf16*  ipw   = (const bf16*) canon[6];
    const float* cw    = (const float*)canon[7];
    const float* cb    = (const float*)canon[8];
    const bf16*  xpw   = (const bf16*) canon[9];
    const bf16*  dtw   = (const bf16*) canon[10];
    const float* dtbia = (const float*)canon[11];
    const float* Alog  = (const float*)canon[12];
    const float* Dpar  = (const float*)canon[13];
    const float* snw   = (const float*)canon[14];
    const float* snb   = (const float*)canon[15];
    const bf16*  opw   = (const bf16*) canon[16];
    const float* nfw   = (const float*)canon[17];
    const float* nfb   = (const float*)canon[18];
    const bf16*  hw    = (const bf16*) canon[19];
    const float* hb    = (const float*)canon[20];

    const int MG  = g*SEQ;
    const int GXm = (MG + 127)/128;       // MFMA grid (M)
    const int nin = g*96;                 // scan inner blocks per chunk

    // dispatch helper: fast path when all dims are tile-clean
    auto launch_gemm = [&](const bf16* A, int lda, const bf16* W, int ldw,
                           float* Cf, bf16* Cb, int ldc,
                           const float* bias, const float* chan_,
                           int M, int N, int K, int epi) {
        dim3 gr((M + 127)/128, (N + 127)/128);
        if ((M & 127) == 0 && (N & 127) == 0 && (K & 31) == 0)
            gemm_mfma_fast<<<gr, blk, 0, stream>>>(A, lda, W, ldw, Cf, Cb, ldc,
                                                   bias, chan_, N, K, epi);
        else
            gemm_mfma<<<gr, blk, 0, stream>>>(A, lda, W, ldw, Cf, Cb, ldc,
                                              bias, chan_, M, N, K, epi);
    };

    // ---- patch embed -> residual (fp32), MFMA epi3 ----
    for (int b0 = 0; b0 < BATCH; b0 += g) {
        gather_patches<<<MG, blk, 0, stream>>>(xin, Ap, b0);
        launch_gemm(Ap, 256, pw, 256,
                    residual + (size_t)b0*SEQ*DM, nullptr, DM,
                    pb, chan, MG, DM, 256, 3);
    }

    for (int l = 0; l < LAYERS; ++l) {
        ln768<<<M_TOK, blk, 0, stream>>>(residual, nw + l*DM, nb + l*DM, hn);
        for (int b0 = 0; b0 < BATCH; b0 += g) {
            const bf16* hng = hn + (size_t)b0*SEQ*DM;
            // in_proj halves (MFMA)
            launch_gemm(hng, DM, ipw + (size_t)l*2*DI*DM, DM,
                        nullptr, xh, DI, nullptr, nullptr, MG, DI, DM, 0);
            launch_gemm(hng, DM, ipw + (size_t)l*2*DI*DM + (size_t)DI*DM, DM,
                        nullptr, zh, DI, nullptr, nullptr, MG, DI, DM, 0);
            conv_silu<<<(MG*(DI/8))/256, blk, 0, stream>>>(xh, cw + (size_t)l*DI*4, cb + l*DI, xc);
            // x_proj (N=80, ragged -> slow path)
            launch_gemm(xc, DI, xpw + (size_t)l*80*DI, DI,
                        nullptr, dbc, 80, nullptr, nullptr, MG, 80, DI, 0);
            // dt_proj + softplus (K=48, ragged -> slow path)
            launch_gemm(dbc, 80, dtw + (size_t)l*DI*DTR, DTR,
                        nullptr, dtb, DI, dtbia + l*DI, nullptr, MG, DI, DTR, 1);
            scan_pass1<<<(NCH-1)*nin, blk, 0, stream>>>(dtb, xc, dbc,
                                                        Alog + (size_t)l*DI*DS,
                                                        hend, Pprod, nin);
            scan_mid<<<nin, blk, 0, stream>>>(hend, Pprod, hstart, nin);
            scan_pass2<<<NCH*nin, blk, 0, stream>>>(dtb, xc, dbc,
                                                    Alog + (size_t)l*DI*DS,
                                                    Dpar + l*DI, hstart, ybuf, nin);
            gate_ln<<<MG, blk, 0, stream>>>(ybuf, zh, snw + l*DI, snb + l*DI, gated);
            // out_proj += residual (MFMA epi2)
            launch_gemm(gated, DI, opw + (size_t)l*DM*DI, DI,
                        residual + (size_t)b0*SEQ*DM, nullptr, DM,
                        nullptr, nullptr, MG, DM, DI, 2);
        }
    }

    ln768<<<M_TOK, blk, 0, stream>>>(residual, nfw, nfb, hn);
    pool_kernel<<<(BATCH*DM)/256, blk, 0, stream>>>(hn, pooled);
    head_kernel<<<(BATCH*NCLS + 255)/256, blk, 0, stream>>>(flag, pooled, hw, hb, d_out);
}

// Round 7
// 3515.468 us; speedup vs baseline: 1.3999x; 1.1257x over previous
//
#include <hip/hip_runtime.h>
#include <hip/hip_bf16.h>

typedef __hip_bfloat16 bf16;
typedef __attribute__((ext_vector_type(8))) short short8;
typedef __attribute__((ext_vector_type(4))) float float4v;

#define BATCH 8
#define SEQ   1568            // 14*14*8 tokens per batch
#define M_TOK (BATCH*SEQ)     // 12544
#define DM    768
#define DI    1536
#define DS    16
#define DTR   48
#define NCLS  1000
#define LAYERS 4
#define CHUNK 112             // scan chunk length (7 tiles of 16)
#define NCH   14              // SEQ / CHUNK

__device__ __forceinline__ float b2f(bf16 v){ return __bfloat162float(v); }
__device__ __forceinline__ bf16  f2b(float v){ return __float2bfloat16(v); }
__device__ __forceinline__ float us2f(unsigned short u){
    unsigned v = ((unsigned)u) << 16; float f; __builtin_memcpy(&f, &v, 4); return f;
}
// async global->LDS, 16B per lane; LDS dest = uniform base + lane*16
__device__ __forceinline__ void gload_lds16(const void* g, void* l){
    __builtin_amdgcn_global_load_lds(
        (const __attribute__((address_space(1))) void*)g,
        (__attribute__((address_space(3))) void*)l, 16, 0, 0);
}
// VALU-pipe cross-lane add via DPP. CTRL immediate (template).
// 0xB1 quad_perm xor1, 0x4E quad_perm xor2
template<int CTRL>
__device__ __forceinline__ float dpp_add(float p){
    int pi; __builtin_memcpy(&pi, &p, 4);
    int mi = __builtin_amdgcn_update_dpp(pi, pi, CTRL, 0xF, 0xF, false);
    float m; __builtin_memcpy(&m, &mi, 4);
    return p + m;
}

// ---------------------------------------------------------------- dtype probe
__global__ void detect_dtype(const unsigned short* __restrict__ probe, unsigned* __restrict__ flag)
{
    if (threadIdx.x == 0 && blockIdx.x == 0) flag[0] = (probe[0] == 0) ? 1u : 0u;  // 1 = fp32
}

__global__ __launch_bounds__(256)
void to_bf16(const unsigned* __restrict__ flag, const void* __restrict__ src,
             bf16* __restrict__ dst, int n)
{
    int i = blockIdx.x*256 + threadIdx.x;
    if (i >= n) return;
    dst[i] = flag[0] ? f2b(((const float*)src)[i]) : ((const bf16*)src)[i];
}

__global__ __launch_bounds__(256)
void to_f32(const unsigned* __restrict__ flag, const void* __restrict__ src,
            float* __restrict__ dst, int n)
{
    int i = blockIdx.x*256 + threadIdx.x;
    if (i >= n) return;
    dst[i] = flag[0] ? ((const float*)src)[i] : b2f(((const bf16*)src)[i]);
}

// ---------------------------------------------------------------- gather patches (per batch-group)
__global__ __launch_bounds__(256)
void gather_patches(const bf16* __restrict__ x, bf16* __restrict__ Ap, int b0)
{
    size_t idx = (size_t)blockIdx.x*256 + threadIdx.x;
    int i = (int)(idx & 255);
    int m = (int)(idx >> 8);
    int b = b0 + m / SEQ, s = m % SEQ;
    int hw = s >> 3, c = s & 7;
    int h = hw / 14, w = hw % 14;
    int p = i >> 4, q = i & 15;
    Ap[idx] = x[(((size_t)(b*8 + c)*224) + h*16 + p)*224 + w*16 + q];
}

// ---------------------------------------------------------------- MFMA GEMM, ragged-safe (128x128, BK=32)
__global__ __launch_bounds__(256)
void gemm_mfma(const bf16* __restrict__ A, int lda,
               const bf16* __restrict__ W, int ldw,
               float* __restrict__ Cf, bf16* __restrict__ Cb, int ldc,
               const float* __restrict__ bias, const float* __restrict__ chan,
               int M, int N, int K, int epi)
{
    __shared__ short As[128*40];   // 32 + 8 pad elems per row (80B stride, 16B aligned)
    __shared__ short Bs[128*40];
    int tid  = threadIdx.x;
    int m0   = blockIdx.x*128, n0 = blockIdx.y*128;
    int lane = tid & 63, wv = tid >> 6;
    int wm = (wv >> 1)*64, wn = (wv & 1)*64;
    int l15 = lane & 15, quad = lane >> 4;

    float4v acc[4][4];
    #pragma unroll
    for (int i = 0; i < 4; ++i)
        #pragma unroll
        for (int j = 0; j < 4; ++j) acc[i][j] = (float4v){0.f,0.f,0.f,0.f};

    const short8 zv8 = {0,0,0,0,0,0,0,0};
    for (int k0 = 0; k0 < K; k0 += 32) {
        #pragma unroll
        for (int u = 0; u < 2; ++u) {
            int c   = tid*2 + u;           // 512 chunks of 16B
            int row = c >> 2, ch = c & 3;
            bool kok = (k0 + ch*8 + 8) <= K;   // K is a multiple of 8
            short8 va = (kok && m0 + row < M)
                ? *(const short8*)((const short*)A + (size_t)(m0+row)*lda + k0 + ch*8) : zv8;
            *(short8*)(As + row*40 + ch*8) = va;
            short8 vb = (kok && n0 + row < N)
                ? *(const short8*)((const short*)W + (size_t)(n0+row)*ldw + k0 + ch*8) : zv8;
            *(short8*)(Bs + row*40 + ch*8) = vb;
        }
        __syncthreads();
        short8 av[4], bv[4];
        #pragma unroll
        for (int i = 0; i < 4; ++i) av[i] = *(const short8*)(As + (wm + i*16 + l15)*40 + quad*8);
        #pragma unroll
        for (int j = 0; j < 4; ++j) bv[j] = *(const short8*)(Bs + (wn + j*16 + l15)*40 + quad*8);
        #pragma unroll
        for (int i = 0; i < 4; ++i)
            #pragma unroll
            for (int j = 0; j < 4; ++j)
                acc[i][j] = __builtin_amdgcn_mfma_f32_16x16x32_bf16(av[i], bv[j], acc[i][j], 0, 0, 0);
        __syncthreads();
    }

    // C/D layout: col = lane&15, row = quad*4 + reg
    #pragma unroll
    for (int i = 0; i < 4; ++i) {
        #pragma unroll
        for (int j = 0; j < 4; ++j) {
            int gn = n0 + wn + j*16 + l15;
            if (gn >= N) continue;
            #pragma unroll
            for (int r = 0; r < 4; ++r) {
                int gm = m0 + wm + i*16 + quad*4 + r;
                if (gm >= M) continue;
                float v = acc[i][j][r];
                size_t off = (size_t)gm*ldc + gn;
                if (epi == 0)      Cb[off] = f2b(v);
                else if (epi == 1) {
                    v += bias[gn];
                    v = (v > 20.f) ? v : log1pf(__expf(v));
                    Cb[off] = f2b(v);
                }
                else if (epi == 2) Cf[off] += v;
                else               Cf[off] = v + bias[gn] + chan[(size_t)(gm & 7)*N + gn];
            }
        }
    }
}

// ---------------------------------------------------------------- MFMA GEMM fast path (m97 recipe)
// Requires M%128==0, N%128==0, K%32==0. Linear [128][32] LDS, global_load_lds dwordx4.
__global__ __launch_bounds__(256)
void gemm_mfma_fast(const bf16* __restrict__ A, int lda,
                    const bf16* __restrict__ W, int ldw,
                    float* __restrict__ Cf, bf16* __restrict__ Cb, int ldc,
                    const float* __restrict__ bias, const float* __restrict__ chan,
                    int N, int K, int epi)
{
    __shared__ short As[128*32];
    __shared__ short Bs[128*32];
    int tid  = threadIdx.x;
    int m0   = blockIdx.x*128, n0 = blockIdx.y*128;
    int lane = tid & 63, wv = tid >> 6;
    int wm = (wv >> 1)*64, wn = (wv & 1)*64;
    int l15 = lane & 15, quad = lane >> 4;

    int srow = (lane >> 2);          // row within 16-row chunk
    int skof = (lane & 3) * 8;       // k element offset within row

    float4v acc[4][4];
    #pragma unroll
    for (int i = 0; i < 4; ++i)
        #pragma unroll
        for (int j = 0; j < 4; ++j) acc[i][j] = (float4v){0.f,0.f,0.f,0.f};

    const short* Ab = (const short*)A;
    const short* Wb = (const short*)W;

    for (int k0 = 0; k0 < K; k0 += 32) {
        #pragma unroll
        for (int u = 0; u < 2; ++u) {
            int c = wv*2 + u;                 // chunk 0..7
            int row = c*16 + srow;
            gload_lds16(Ab + (size_t)(m0+row)*lda + k0 + skof, As + c*512);
            gload_lds16(Wb + (size_t)(n0+row)*ldw + k0 + skof, Bs + c*512);
        }
        __syncthreads();                       // drains vmcnt (compiler-inserted)
        short8 av[4], bv[4];
        #pragma unroll
        for (int i = 0; i < 4; ++i) av[i] = *(const short8*)(As + (wm + i*16 + l15)*32 + quad*8);
        #pragma unroll
        for (int j = 0; j < 4; ++j) bv[j] = *(const short8*)(Bs + (wn + j*16 + l15)*32 + quad*8);
        #pragma unroll
        for (int i = 0; i < 4; ++i)
            #pragma unroll
            for (int j = 0; j < 4; ++j)
                acc[i][j] = __builtin_amdgcn_mfma_f32_16x16x32_bf16(av[i], bv[j], acc[i][j], 0, 0, 0);
        __syncthreads();
    }

    #pragma unroll
    for (int i = 0; i < 4; ++i) {
        #pragma unroll
        for (int j = 0; j < 4; ++j) {
            int gn = n0 + wn + j*16 + l15;
            #pragma unroll
            for (int r = 0; r < 4; ++r) {
                int gm = m0 + wm + i*16 + quad*4 + r;
                float v = acc[i][j][r];
                size_t off = (size_t)gm*ldc + gn;
                if (epi == 0)      Cb[off] = f2b(v);
                else if (epi == 1) {
                    v += bias[gn];
                    v = (v > 20.f) ? v : log1pf(__expf(v));
                    Cb[off] = f2b(v);
                }
                else if (epi == 2) Cf[off] += v;
                else               Cf[off] = v + bias[gn] + chan[(size_t)(gm & 7)*N + gn];
            }
        }
    }
}

// ---------------------------------------------------------------- LayerNorm 768 (fp32 in, bf16 out)
__global__ __launch_bounds__(256)
void ln768(const float* __restrict__ X, const float* __restrict__ w,
           const float* __restrict__ bb, bf16* __restrict__ out)
{
    __shared__ float red[8];
    size_t t = blockIdx.x;
    const float* x = X + t*DM;
    float v[3]; float s = 0.f, s2 = 0.f;
    #pragma unroll
    for (int r = 0; r < 3; ++r) {
        v[r] = x[threadIdx.x + 256*r];
        s += v[r]; s2 += v[r]*v[r];
    }
    #pragma unroll
    for (int o = 32; o; o >>= 1) { s += __shfl_down(s, o, 64); s2 += __shfl_down(s2, o, 64); }
    if ((threadIdx.x & 63) == 0) { red[threadIdx.x >> 6] = s; red[(threadIdx.x >> 6) + 4] = s2; }
    __syncthreads();
    s  = red[0]+red[1]+red[2]+red[3];
    s2 = red[4]+red[5]+red[6]+red[7];
    float mu  = s * (1.f/DM);
    float inv = rsqrtf(fmaxf(s2*(1.f/DM) - mu*mu, 0.f) + 1e-5f);
    #pragma unroll
    for (int r = 0; r < 3; ++r) {
        int i = threadIdx.x + 256*r;
        out[t*DM + i] = f2b((v[r]-mu)*inv*w[i] + bb[i]);
    }
}

// ---------------------------------------------------------------- causal depthwise conv (k=4) + silu
// vectorized: 8 d per thread, short8 loads/stores (G13)
__global__ __launch_bounds__(256)
void conv_silu(const bf16* __restrict__ xh, const float* __restrict__ cw,
               const float* __restrict__ cb, bf16* __restrict__ xc)
{
    size_t idx = (size_t)blockIdx.x*256 + threadIdx.x;   // < g*SEQ*DI/8
    int dv = (int)(idx % (DI/8));
    int m  = (int)(idx / (DI/8));
    int b = m / SEQ, t = m % SEQ;                        // local batch
    int d = dv*8;

    float4v cwq[8];
    #pragma unroll
    for (int j = 0; j < 8; ++j) cwq[j] = *(const float4v*)(cw + (size_t)(d+j)*4);

    float acc[8];
    #pragma unroll
    for (int j = 0; j < 8; ++j) acc[j] = cb[d+j];

    #pragma unroll
    for (int k = 0; k < 4; ++k) {
        int tt = t + k - 3;
        if (tt >= 0) {
            short8 v = *(const short8*)((const short*)xh + (size_t)(b*SEQ + tt)*DI + d);
            #pragma unroll
            for (int j = 0; j < 8; ++j)
                acc[j] += us2f((unsigned short)v[j]) * cwq[j][k];
        }
    }
    short8 o;
    #pragma unroll
    for (int j = 0; j < 8; ++j) {
        float sig = 1.f/(1.f + __expf(-acc[j]));
        bf16 r = f2b(acc[j]*sig);
        unsigned short u; __builtin_memcpy(&u, &r, 2); o[j] = (short)u;
    }
    *(short8*)((short*)xc + idx*8) = o;
}

// ---------------------------------------------------------------- selective scan v7: chunked 2-pass,
// 4 states/lane mapping (64 d x 4 state-quads per 256-thread block). Amortizes
// dtv/xv/dtx and the reduction over 4 in-lane states (~4 VALU ops/state vs ~13);
// 16-state reduction = 2 quad_perm DPP adds (quad = one d). Double-buffered
// reg-staged LDS: dt/x [64][20] (b128 over 4 steps), B/C [16][16] (b128/step).
// hend/Pprod/hstart layout: float4 per (block,thread): [(c, r, tid, k)].

__global__ __launch_bounds__(256)
void scan_pass1(const bf16* __restrict__ dt, const bf16* __restrict__ x,
                const bf16* __restrict__ dbc, const float* __restrict__ Alog,
                float* __restrict__ hend, float* __restrict__ Pprod, int nin2)
{
    __shared__ float dtT[2][64][20], xT[2][64][20];
    __shared__ float BsT[2][16][16];
    int c  = blockIdx.x / nin2;          // chunk 0..NCH-2
    int r  = blockIdx.x % nin2;
    int b  = r / 24;
    int d0 = (r % 24) * 64;
    int tid = threadIdx.x;
    int sq = tid & 3;        // state quad: states sq*4..sq*4+3
    int dl = tid >> 2;       // d-chain 0..63
    int d  = d0 + dl;

    float4v Aq = *(const float4v*)(Alog + (size_t)d*DS + sq*4);
    float A2[4], h[4];
    #pragma unroll
    for (int k = 0; k < 4; ++k) { A2[k] = -__expf(Aq[k]) * 1.44269504f; h[k] = 0.f; }
    float sdt = 0.f;

    int js = tid >> 4, dg = tid & 15;        // dt/x staging: step js, d-group dg*4
    bool doB = tid < 64;
    int j2 = tid >> 2;                       // B staging step (tid<64)

    const unsigned short* pdt = (const unsigned short*)dt + ((size_t)b*SEQ + js)*DI + d0 + dg*4;
    const unsigned short* px  = (const unsigned short*)x  + ((size_t)b*SEQ + js)*DI + d0 + dg*4;
    const unsigned short* pbc = (const unsigned short*)dbc + ((size_t)b*SEQ + (j2 & 15))*80 + DTR + sq*4;
    int tbase = c * CHUNK;
    const int NT = CHUNK/16;

    ushort4 vdt, vx, vbc;
    auto stage = [&](int buf){
        dtT[buf][dg*4+0][js] = us2f(vdt.x); dtT[buf][dg*4+1][js] = us2f(vdt.y);
        dtT[buf][dg*4+2][js] = us2f(vdt.z); dtT[buf][dg*4+3][js] = us2f(vdt.w);
        xT [buf][dg*4+0][js] = us2f(vx.x);  xT [buf][dg*4+1][js] = us2f(vx.y);
        xT [buf][dg*4+2][js] = us2f(vx.z);  xT [buf][dg*4+3][js] = us2f(vx.w);
        if (doB)
            *(float4v*)&BsT[buf][j2][sq*4] =
                (float4v){us2f(vbc.x), us2f(vbc.y), us2f(vbc.z), us2f(vbc.w)};
    };
    auto fetch = [&](int T){
        vdt = *(const ushort4*)(pdt + (size_t)(tbase + T*16)*DI);
        vx  = *(const ushort4*)(px  + (size_t)(tbase + T*16)*DI);
        if (doB) vbc = *(const ushort4*)(pbc + (size_t)(tbase + T*16)*80);
    };

    fetch(0); stage(0); fetch(1);
    __syncthreads();

    for (int t = 0; t < NT; ++t) {
        int cur = t & 1;
        if (t+1 < NT) stage(cur^1);
        if (t+2 < NT) fetch(t+2);
        #pragma unroll
        for (int jj = 0; jj < 16; jj += 4) {
            float4v dtq = *(const float4v*)&dtT[cur][dl][jj];
            float4v xq  = *(const float4v*)&xT [cur][dl][jj];
            #pragma unroll
            for (int k2 = 0; k2 < 4; ++k2) {
                float dtv = dtq[k2];
                float dtx = dtv * xq[k2];
                float4v Bq = *(const float4v*)&BsT[cur][jj+k2][sq*4];
                #pragma unroll
                for (int k = 0; k < 4; ++k)
                    h[k] = exp2f(dtv*A2[k])*h[k] + dtx*Bq[k];
                sdt += dtv;
            }
        }
        __syncthreads();
    }
    size_t o = (((size_t)c*nin2 + r)*256 + tid)*4;
    *(float4v*)(hend + o) = (float4v){h[0], h[1], h[2], h[3]};
    *(float4v*)(Pprod + o) = (float4v){exp2f(A2[0]*sdt), exp2f(A2[1]*sdt),
                                       exp2f(A2[2]*sdt), exp2f(A2[3]*sdt)};
}

__global__ __launch_bounds__(256)
void scan_mid(const float* __restrict__ hend, const float* __restrict__ Pprod,
              float* __restrict__ hstart, int nin2)
{
    int r = blockIdx.x, tid = threadIdx.x;
    float4v h = (float4v){0.f,0.f,0.f,0.f};
    *(float4v*)(hstart + ((size_t)r*256 + tid)*4) = h;
    for (int c = 1; c < NCH; ++c) {
        size_t p = (((size_t)(c-1)*nin2 + r)*256 + tid)*4;
        float4v P  = *(const float4v*)(Pprod + p);
        float4v he = *(const float4v*)(hend + p);
        h = P*h + he;
        *(float4v*)(hstart + (((size_t)c*nin2 + r)*256 + tid)*4) = h;
    }
}

__global__ __launch_bounds__(256)
void scan_pass2(const bf16* __restrict__ dt, const bf16* __restrict__ x,
                const bf16* __restrict__ dbc, const float* __restrict__ Alog,
                const float* __restrict__ Dpar, const float* __restrict__ hstart,
                bf16* __restrict__ y, int nin2)
{
    __shared__ float dtT[2][64][20], xT[2][64][20];
    __shared__ float BsT[2][16][16], CsT[2][16][16];
    __shared__ bf16  ys[16][64];
    int c  = blockIdx.x / nin2;
    int r  = blockIdx.x % nin2;
    int b  = r / 24;
    int d0 = (r % 24) * 64;
    int tid = threadIdx.x;
    int sq = tid & 3;
    int dl = tid >> 2;
    int d  = d0 + dl;

    float4v Aq = *(const float4v*)(Alog + (size_t)d*DS + sq*4);
    float A2[4], h[4];
    {
        float4v h0 = *(const float4v*)(hstart + (((size_t)c*nin2 + r)*256 + tid)*4);
        #pragma unroll
        for (int k = 0; k < 4; ++k) { A2[k] = -__expf(Aq[k]) * 1.44269504f; h[k] = h0[k]; }
    }
    float Dv = Dpar[d];

    int js = tid >> 4, dg = tid & 15;
    bool doBC = tid < 128;
    int j2 = (tid & 63) >> 2;

    const unsigned short* pdt = (const unsigned short*)dt + ((size_t)b*SEQ + js)*DI + d0 + dg*4;
    const unsigned short* px  = (const unsigned short*)x  + ((size_t)b*SEQ + js)*DI + d0 + dg*4;
    const unsigned short* pbc = (const unsigned short*)dbc + ((size_t)b*SEQ + j2)*80 + DTR
                                + ((tid >= 64) ? DS : 0) + sq*4;
    float* bc0 = (tid < 64) ? &BsT[0][j2][sq*4] : &CsT[0][j2][sq*4];
    int tbase = c * CHUNK;
    const int NT = CHUNK/16;

    ushort4 vdt, vx, vbc;
    auto stage = [&](int buf){
        dtT[buf][dg*4+0][js] = us2f(vdt.x); dtT[buf][dg*4+1][js] = us2f(vdt.y);
        dtT[buf][dg*4+2][js] = us2f(vdt.z); dtT[buf][dg*4+3][js] = us2f(vdt.w);
        xT [buf][dg*4+0][js] = us2f(vx.x);  xT [buf][dg*4+1][js] = us2f(vx.y);
        xT [buf][dg*4+2][js] = us2f(vx.z);  xT [buf][dg*4+3][js] = us2f(vx.w);
        if (doBC)
            *(float4v*)(bc0 + (size_t)buf*256) =
                (float4v){us2f(vbc.x), us2f(vbc.y), us2f(vbc.z), us2f(vbc.w)};
    };
    auto fetch = [&](int T){
        vdt = *(const ushort4*)(pdt + (size_t)(tbase + T*16)*DI);
        vx  = *(const ushort4*)(px  + (size_t)(tbase + T*16)*DI);
        if (doBC) vbc = *(const ushort4*)(pbc + (size_t)(tbase + T*16)*80);
    };

    fetch(0); stage(0); fetch(1);
    __syncthreads();

    for (int t = 0; t < NT; ++t) {
        int cur = t & 1;
        if (t+1 < NT) stage(cur^1);
        if (t+2 < NT) fetch(t+2);

        #pragma unroll
        for (int jj = 0; jj < 16; jj += 4) {
            float4v dtq = *(const float4v*)&dtT[cur][dl][jj];
            float4v xq  = *(const float4v*)&xT [cur][dl][jj];
            #pragma unroll
            for (int k2 = 0; k2 < 4; ++k2) {
                float dtv = dtq[k2];
                float xv  = xq[k2];
                float dtx = dtv * xv;
                float4v Bq = *(const float4v*)&BsT[cur][jj+k2][sq*4];
                float4v Cq = *(const float4v*)&CsT[cur][jj+k2][sq*4];
                float p = 0.f;
                #pragma unroll
                for (int k = 0; k < 4; ++k) {
                    h[k] = exp2f(dtv*A2[k])*h[k] + dtx*Bq[k];
                    p += h[k]*Cq[k];
                }
                p = dpp_add<0xB1>(p);    // quad_perm xor1 (within one d's quad)
                p = dpp_add<0x4E>(p);    // quad_perm xor2
                if (sq == 0) ys[jj+k2][dl] = f2b(p + Dv*xv);
            }
        }
        __syncthreads();                 // ys ready + next buf staged
        {
            size_t rowm = (size_t)(b*SEQ + tbase + t*16 + js);
            ushort4 vy = *(const ushort4*)((const unsigned short*)&ys[js][0] + dg*4);
            *(ushort4*)((unsigned short*)y + rowm*DI + d0 + dg*4) = vy;
        }
        __syncthreads();                 // ys consumed
    }
}

// ---------------------------------------------------------------- LN(1536) * silu(z) gate
__global__ __launch_bounds__(256)
void gate_ln(const bf16* __restrict__ y, const bf16* __restrict__ z,
             const float* __restrict__ w, const float* __restrict__ bb,
             bf16* __restrict__ out)
{
    __shared__ float red[8];
    size_t t = blockIdx.x;
    const bf16* yy = y + t*DI;
    const bf16* zz = z + t*DI;
    float v[6]; float s = 0.f, s2 = 0.f;
    #pragma unroll
    for (int r = 0; r < 6; ++r) {
        v[r] = b2f(yy[threadIdx.x + 256*r]);
        s += v[r]; s2 += v[r]*v[r];
    }
    #pragma unroll
    for (int o = 32; o; o >>= 1) { s += __shfl_down(s, o, 64); s2 += __shfl_down(s2, o, 64); }
    if ((threadIdx.x & 63) == 0) { red[threadIdx.x >> 6] = s; red[(threadIdx.x >> 6) + 4] = s2; }
    __syncthreads();
    s  = red[0]+red[1]+red[2]+red[3];
    s2 = red[4]+red[5]+red[6]+red[7];
    float mu  = s * (1.f/DI);
    float inv = rsqrtf(fmaxf(s2*(1.f/DI) - mu*mu, 0.f) + 1e-5f);
    #pragma unroll
    for (int r = 0; r < 6; ++r) {
        int i = threadIdx.x + 256*r;
        float zv = b2f(zz[i]);
        float sig = 1.f/(1.f + __expf(-zv));
        out[t*DI + i] = f2b(((v[r]-mu)*inv*w[i] + bb[i]) * (zv*sig));
    }
}

// ---------------------------------------------------------------- mean pool over tokens
__global__ __launch_bounds__(256)
void pool_kernel(const bf16* __restrict__ hf, float* __restrict__ pooled)
{
    int idx = blockIdx.x*256 + threadIdx.x;   // < BATCH*DM
    int b = idx / DM, dm = idx % DM;
    const bf16* p = hf + (size_t)b*SEQ*DM + dm;
    float s = 0.f;
    for (int t = 0; t < SEQ; ++t) s += b2f(p[(size_t)t*DM]);
    pooled[idx] = s * (1.f/SEQ);
}

// ---------------------------------------------------------------- classifier head
__global__ __launch_bounds__(256)
void head_kernel(const unsigned* __restrict__ flag,
                 const float* __restrict__ pooled, const bf16* __restrict__ hw,
                 const float* __restrict__ hb, void* __restrict__ out)
{
    int idx = blockIdx.x*256 + threadIdx.x;
    if (idx >= BATCH*NCLS) return;
    int b = idx & 7, n = idx >> 3;
    const float* p = pooled + b*DM;
    const unsigned short* w = (const unsigned short*)hw + (size_t)n*DM;
    float acc = hb[n];
    for (int k = 0; k < DM; k += 4) {
        ushort4 wv = *(const ushort4*)(w + k);
        acc += p[k]*us2f(wv.x) + p[k+1]*us2f(wv.y) + p[k+2]*us2f(wv.z) + p[k+3]*us2f(wv.w);
    }
    int o = b*NCLS + n;
    if (flag[0]) ((float*)out)[o] = acc;
    else         ((bf16*)out)[o]  = f2b(acc);
}

// ================================================================ launcher
extern "C" void kernel_launch(void* const* d_in, const int* in_sizes, int n_in,
                              void* d_out, int out_size, void* d_ws, size_t ws_size,
                              hipStream_t stream)
{
    (void)n_in; (void)out_size;
    dim3 blk(256);

    const bool is_f32[21] = { false, false, true, true, true, true, false, true, true,
                              false, false, true,  true, true, true, true, false,
                              true,  true,  false, true };

    size_t off = 0;
    auto carve = [&](size_t bytes) -> void* {
        void* q = (char*)d_ws + off;
        off += (bytes + 255) & ~(size_t)255;
        return q;
    };

    unsigned* flag = (unsigned*)carve(256);
    void* canon[21];
    for (int i = 0; i < 21; ++i)
        canon[i] = carve((size_t)in_sizes[i] * (is_f32[i] ? 4 : 2));

    float* residual = (float*)carve((size_t)M_TOK*DM*4);
    bf16*  hn       = (bf16*) carve((size_t)M_TOK*DM*2);
    float* pooled   = (float*)carve((size_t)BATCH*DM*4);

    const size_t scanbuf1 = (size_t)NCH*96*256*4;   // per g-unit, per array (== NCH*24*256*4st*4B)
    const size_t inner1 = 4*(((size_t)SEQ*DI*2 + 255) & ~(size_t)255)
                          + (((size_t)SEQ*80*2 + 255) & ~(size_t)255)
                          + 3*((scanbuf1 + 255) & ~(size_t)255);
    int g = 8;
    while (g > 1 && off + (size_t)g*inner1 > ws_size) g >>= 1;

    bf16* xh  = (bf16*)carve((size_t)g*SEQ*DI*2);   // also Ap / ybuf
    bf16* zh  = (bf16*)carve((size_t)g*SEQ*DI*2);
    bf16* xc  = (bf16*)carve((size_t)g*SEQ*DI*2);
    bf16* dtb = (bf16*)carve((size_t)g*SEQ*DI*2);   // also gated
    bf16* dbc = (bf16*)carve((size_t)g*SEQ*80*2);
    float* hend   = (float*)carve((size_t)g*scanbuf1);
    float* Pprod  = (float*)carve((size_t)g*scanbuf1);
    float* hstart = (float*)carve((size_t)g*scanbuf1);
    bf16* Ap    = xh;
    bf16* ybuf  = xh;
    bf16* gated = dtb;

    detect_dtype<<<1, 64, 0, stream>>>((const unsigned short*)d_in[4], flag);
    for (int i = 0; i < 21; ++i) {
        int n = in_sizes[i];
        int gr = (n + 255)/256;
        if (is_f32[i]) to_f32 <<<gr, blk, 0, stream>>>(flag, d_in[i], (float*)canon[i], n);
        else           to_bf16<<<gr, blk, 0, stream>>>(flag, d_in[i], (bf16*) canon[i], n);
    }

    const bf16*  xin   = (const bf16*) canon[0];
    const bf16*  pw    = (const bf16*) canon[1];
    const float* pb    = (const float*)canon[2];
    const float* chan  = (const float*)canon[3];
    const float* nw    = (const float*)canon[4];
    const float* nb    = (const float*)canon[5];
    const bf16*  ipw   = (const bf16*) canon[6];
    const float* cw    = (const float*)canon[7];
    const float* cb    = (const float*)canon[8];
    const bf16*  xpw   = (const bf16*) canon[9];
    const bf16*  dtw   = (const bf16*) canon[10];
    const float* dtbia = (const float*)canon[11];
    const float* Alog  = (const float*)canon[12];
    const float* Dpar  = (const float*)canon[13];
    const float* snw   = (const float*)canon[14];
    const float* snb   = (const float*)canon[15];
    const bf16*  opw   = (const bf16*) canon[16];
    const float* nfw   = (const float*)canon[17];
    const float* nfb   = (const float*)canon[18];
    const bf16*  hw    = (const bf16*) canon[19];
    const float* hb    = (const float*)canon[20];

    const int MG  = g*SEQ;
    const int GXm = (MG + 127)/128;       // MFMA grid (M)
    const int nin2 = g*24;                // scan blocks per chunk (64 d each)

    // dispatch helper: fast path when all dims are tile-clean
    auto launch_gemm = [&](const bf16* A, int lda, const bf16* W, int ldw,
                           float* Cf, bf16* Cb, int ldc,
                           const float* bias, const float* chan_,
                           int M, int N, int K, int epi) {
        dim3 gr((M + 127)/128, (N + 127)/128);
        if ((M & 127) == 0 && (N & 127) == 0 && (K & 31) == 0)
            gemm_mfma_fast<<<gr, blk, 0, stream>>>(A, lda, W, ldw, Cf, Cb, ldc,
                                                   bias, chan_, N, K, epi);
        else
            gemm_mfma<<<gr, blk, 0, stream>>>(A, lda, W, ldw, Cf, Cb, ldc,
                                              bias, chan_, M, N, K, epi);
    };

    // ---- patch embed -> residual (fp32), MFMA epi3 ----
    for (int b0 = 0; b0 < BATCH; b0 += g) {
        gather_patches<<<MG, blk, 0, stream>>>(xin, Ap, b0);
        launch_gemm(Ap, 256, pw, 256,
                    residual + (size_t)b0*SEQ*DM, nullptr, DM,
                    pb, chan, MG, DM, 256, 3);
    }

    for (int l = 0; l < LAYERS; ++l) {
        ln768<<<M_TOK, blk, 0, stream>>>(residual, nw + l*DM, nb + l*DM, hn);
        for (int b0 = 0; b0 < BATCH; b0 += g) {
            const bf16* hng = hn + (size_t)b0*SEQ*DM;
            // in_proj halves (MFMA)
            launch_gemm(hng, DM, ipw + (size_t)l*2*DI*DM, DM,
                        nullptr, xh, DI, nullptr, nullptr, MG, DI, DM, 0);
            launch_gemm(hng, DM, ipw + (size_t)l*2*DI*DM + (size_t)DI*DM, DM,
                        nullptr, zh, DI, nullptr, nullptr, MG, DI, DM, 0);
            conv_silu<<<(MG*(DI/8))/256, blk, 0, stream>>>(xh, cw + (size_t)l*DI*4, cb + l*DI, xc);
            // x_proj (N=80, ragged -> slow path)
            launch_gemm(xc, DI, xpw + (size_t)l*80*DI, DI,
                        nullptr, dbc, 80, nullptr, nullptr, MG, 80, DI, 0);
            // dt_proj + softplus (K=48, ragged -> slow path)
            launch_gemm(dbc, 80, dtw + (size_t)l*DI*DTR, DTR,
                        nullptr, dtb, DI, dtbia + l*DI, nullptr, MG, DI, DTR, 1);
            scan_pass1<<<(NCH-1)*nin2, blk, 0, stream>>>(dtb, xc, dbc,
                                                         Alog + (size_t)l*DI*DS,
                                                         hend, Pprod, nin2);
            scan_mid<<<nin2, blk, 0, stream>>>(hend, Pprod, hstart, nin2);
            scan_pass2<<<NCH*nin2, blk, 0, stream>>>(dtb, xc, dbc,
                                                     Alog + (size_t)l*DI*DS,
                                                     Dpar + l*DI, hstart, ybuf, nin2);
            gate_ln<<<MG, blk, 0, stream>>>(ybuf, zh, snw + l*DI, snb + l*DI, gated);
            // out_proj += residual (MFMA epi2)
            launch_gemm(gated, DI, opw + (size_t)l*DM*DI, DI,
                        residual + (size_t)b0*SEQ*DM, nullptr, DM,
                        nullptr, nullptr, MG, DM, DI, 2);
        }
    }

    ln768<<<M_TOK, blk, 0, stream>>>(residual, nfw, nfb, hn);
    pool_kernel<<<(BATCH*DM)/256, blk, 0, stream>>>(hn, pooled);
    head_kernel<<<(BATCH*NCLS + 255)/256, blk, 0, stream>>>(flag, pooled, hw, hb, d_out);
}